// Round 9
// baseline (872.551 us; speedup 1.0000x reference)
//
#include <hip/hip_runtime.h>
#include <cstdint>
#include <cstddef>

#define N_NODES 50000
#define N_EDGES 800000
#define DIM_H   128
#define DIM_P   64     // propagation width after commuting W3
#define DIM_OUT 1000
#define OUT_PAD 1024   // padded col count for MFMA tiles
#define KHOPS   10
#define BN_EPS  1e-5f

static inline int ceil_div(int a, int b) { return (a + b - 1) / b; }

typedef short  bf16x8  __attribute__((ext_vector_type(8)));
typedef float  floatx4 __attribute__((ext_vector_type(4)));

__device__ __forceinline__ unsigned short f2bf_rne(float v) {
    unsigned int u = __float_as_uint(v);
    return (unsigned short)((u + 0x7fffu + ((u >> 16) & 1u)) >> 16);
}
__device__ __forceinline__ float bf2f(unsigned short u) {
    return __uint_as_float((unsigned int)u << 16);
}

// ------- init: softmax(att) + Wout transpose/bf16 + zero st/deg, one kernel ---
__global__ void init_all(const float* __restrict__ att, float* __restrict__ w,
                         const float* __restrict__ Wout, unsigned short* __restrict__ WT,
                         double* __restrict__ st, int* __restrict__ deg) {
    const int gid = blockIdx.x * blockDim.x + threadIdx.x;
    const int stride = gridDim.x * blockDim.x;
    if (gid == 0) {
        float mx = att[0];
        for (int i = 1; i < KHOPS + 1; ++i) mx = fmaxf(mx, att[i]);
        float e[KHOPS + 1];
        float s = 0.f;
        for (int i = 0; i < KHOPS + 1; ++i) { e[i] = expf(att[i] - mx); s += e[i]; }
        for (int i = 0; i < KHOPS + 1; ++i) w[i] = e[i] / s;
    }
    for (int i = gid; i < 640; i += stride) st[i] = 0.0;
    for (int i = gid; i < N_NODES; i += stride) deg[i] = 0;
    for (int i = gid; i < OUT_PAD * DIM_P; i += stride) {
        int c = i >> 6, k = i & 63;
        WT[i] = (c < DIM_OUT) ? f2bf_rne(Wout[(size_t)k * DIM_OUT + c]) : (unsigned short)0;
    }
}

// ---------------- CSR build ----------------
__global__ void count_deg(const int* __restrict__ dst, int* __restrict__ deg, int ne) {
    int i = blockIdx.x * blockDim.x + threadIdx.x;
    if (i < ne) atomicAdd(&deg[dst[i]], 1);
}

// local inclusive scan per 1024-block (shuffle-based, 3 barriers)
__global__ __launch_bounds__(1024) void scan_local(const int* __restrict__ deg,
                                                   int* __restrict__ row_ptr,
                                                   int* __restrict__ bsums, int n) {
    __shared__ int wsum[16];
    const int i = blockIdx.x * 1024 + threadIdx.x;
    const int lane = threadIdx.x & 63, w = threadIdx.x >> 6;
    int v = (i < n) ? deg[i] : 0;
    int s = v;
#pragma unroll
    for (int d = 1; d < 64; d <<= 1) {
        int t = __shfl_up(s, d, 64);
        if (lane >= d) s += t;
    }
    if (lane == 63) wsum[w] = s;
    __syncthreads();
    if (w == 0) {
        int x = (lane < 16) ? wsum[lane] : 0;
#pragma unroll
        for (int d = 1; d < 16; d <<= 1) {
            int t = __shfl_up(x, d, 64);
            if (lane >= d) x += t;
        }
        if (lane < 16) wsum[lane] = x;
    }
    __syncthreads();
    int incl = s + ((w > 0) ? wsum[w - 1] : 0);
    if (i < n) row_ptr[i + 1] = incl;
    if (threadIdx.x == 1023) bsums[blockIdx.x] = incl;
}

// add block offsets (block-sum exclusive scan redone per block in wave 0);
// also derive fill-cursor (exclusive start) in-place in deg
__global__ void scan_finish(int* __restrict__ row_ptr, int* __restrict__ deg,
                            const int* __restrict__ bsums, int n, int nb) {
    __shared__ int boff[64];
    if (threadIdx.x < 64) {
        int lane = threadIdx.x;
        int v = (lane < nb) ? bsums[lane] : 0;
        int s = v;
#pragma unroll
        for (int d = 1; d < 64; d <<= 1) {
            int t = __shfl_up(s, d, 64);
            if (lane >= d) s += t;
        }
        boff[lane] = s - v;   // exclusive prefix
    }
    __syncthreads();
    int i = blockIdx.x * blockDim.x + threadIdx.x;
    if (i < n) {
        int incl = row_ptr[i + 1] + boff[i >> 10];
        row_ptr[i + 1] = incl;
        deg[i] = incl - deg[i];   // cursor = exclusive prefix
    }
    if (i == 0) row_ptr[0] = 0;
}

__global__ void fill_csr(const int* __restrict__ src, const int* __restrict__ dst,
                         int* __restrict__ cursor, int* __restrict__ col, int ne) {
    int i = blockIdx.x * blockDim.x + threadIdx.x;
    if (i < ne) {
        int d = dst[i];
        int pos = atomicAdd(&cursor[d], 1);
        col[pos] = src[i];
    }
}

// ---------------- fused GEMM: C[n,M] = act(A) @ W -------------------
// act(A) row = relu(A*sc+sh) [if stA] + relu(A2*sc2+sh2) [if A2]; BN scale/shift
// computed IN-KERNEL from double stats (st, gamma, beta) — replaces bn_finalize.
// STATS: column (sum, sumsq) of C accumulated into stOut via double atomics.
// OBF: C stored as bf16 (propagation hop state); C2 = w0p[0]*C stays fp32.
template<int KD, int CPB, bool STATS, bool OBF>
__global__ __launch_bounds__(256) void gemm_fused(
    const float* __restrict__ A,  const double* __restrict__ stA,
    const float* __restrict__ gA, const float* __restrict__ beA,
    const float* __restrict__ A2, const double* __restrict__ stA2,
    const float* __restrict__ gA2, const float* __restrict__ beA2,
    const float* __restrict__ W,
    float* __restrict__ C, float* __restrict__ C2, const float* __restrict__ w0p,
    double* __restrict__ stOut, int n, int M) {
    constexpr int CG  = CPB / 4;     // col groups per block
    constexpr int RG  = 256 / CG;    // row groups
    constexpr int RPT = 64 / RG;     // rows per thread
    __shared__ float As[64][KD + 4];
    __shared__ float scA_l[2][KD];
    __shared__ float scA2_l[2][KD];

    const int tid  = threadIdx.x;
    const int cg   = tid % CG;
    const int rg   = tid / CG;
    const int row0 = blockIdx.x * 64;
    const int col0 = blockIdx.y * CPB + cg * 4;

    // inline bn_finalize (identical math to the old kernel)
    if (stA && tid < KD) {
        double m = stA[tid] / n;
        double v = stA[KD + tid] / n - m * m;
        float scale = gA[tid] * rsqrtf((float)v + BN_EPS);
        scA_l[0][tid] = scale;
        scA_l[1][tid] = beA[tid] - (float)m * scale;
    }
    if (A2 && tid < KD) {
        double m = stA2[tid] / n;
        double v = stA2[KD + tid] / n - m * m;
        float scale = gA2[tid] * rsqrtf((float)v + BN_EPS);
        scA2_l[0][tid] = scale;
        scA2_l[1][tid] = beA2[tid] - (float)m * scale;
    }
    if (stA || A2) __syncthreads();

    constexpr int VECS = 64 * KD / 4;
    for (int i = tid; i < VECS; i += 256) {
        int r  = i / (KD / 4);
        int k4 = (i % (KD / 4)) * 4;
        float4 v = make_float4(0.f, 0.f, 0.f, 0.f);
        int row = row0 + r;
        if (row < n) {
            v = *reinterpret_cast<const float4*>(A + (size_t)row * KD + k4);
            if (stA) {
                float4 sc = *reinterpret_cast<const float4*>(&scA_l[0][k4]);
                float4 sh = *reinterpret_cast<const float4*>(&scA_l[1][k4]);
                v.x = fmaxf(v.x * sc.x + sh.x, 0.f);
                v.y = fmaxf(v.y * sc.y + sh.y, 0.f);
                v.z = fmaxf(v.z * sc.z + sh.z, 0.f);
                v.w = fmaxf(v.w * sc.w + sh.w, 0.f);
            }
            if (A2) {
                float4 u  = *reinterpret_cast<const float4*>(A2 + (size_t)row * KD + k4);
                float4 sc = *reinterpret_cast<const float4*>(&scA2_l[0][k4]);
                float4 sh = *reinterpret_cast<const float4*>(&scA2_l[1][k4]);
                v.x += fmaxf(u.x * sc.x + sh.x, 0.f);
                v.y += fmaxf(u.y * sc.y + sh.y, 0.f);
                v.z += fmaxf(u.z * sc.z + sh.z, 0.f);
                v.w += fmaxf(u.w * sc.w + sh.w, 0.f);
            }
        }
        *reinterpret_cast<float4*>(&As[r][k4]) = v;
    }
    __syncthreads();

    float acc[RPT][4];
#pragma unroll
    for (int r = 0; r < RPT; ++r)
#pragma unroll
        for (int c = 0; c < 4; ++c) acc[r][c] = 0.f;

    if (col0 < M) {
        for (int k4 = 0; k4 < KD; k4 += 4) {
            float4 w0 = *reinterpret_cast<const float4*>(W + (size_t)(k4 + 0) * M + col0);
            float4 w1 = *reinterpret_cast<const float4*>(W + (size_t)(k4 + 1) * M + col0);
            float4 w2 = *reinterpret_cast<const float4*>(W + (size_t)(k4 + 2) * M + col0);
            float4 w3 = *reinterpret_cast<const float4*>(W + (size_t)(k4 + 3) * M + col0);
#pragma unroll
            for (int r = 0; r < RPT; ++r) {
                float4 a = *reinterpret_cast<const float4*>(&As[rg * RPT + r][k4]);
                acc[r][0] += a.x * w0.x + a.y * w1.x + a.z * w2.x + a.w * w3.x;
                acc[r][1] += a.x * w0.y + a.y * w1.y + a.z * w2.y + a.w * w3.y;
                acc[r][2] += a.x * w0.z + a.y * w1.z + a.z * w2.z + a.w * w3.z;
                acc[r][3] += a.x * w0.w + a.y * w1.w + a.z * w2.w + a.w * w3.w;
            }
        }

        const float w0s = C2 ? w0p[0] : 0.f;
#pragma unroll
        for (int r = 0; r < RPT; ++r) {
            int row = row0 + rg * RPT + r;
            if (row < n) {
                float4 o = make_float4(acc[r][0], acc[r][1], acc[r][2], acc[r][3]);
                if (OBF) {
                    unsigned short* cb = reinterpret_cast<unsigned short*>(C);
                    ushort4 p;
                    p.x = f2bf_rne(o.x); p.y = f2bf_rne(o.y);
                    p.z = f2bf_rne(o.z); p.w = f2bf_rne(o.w);
                    *reinterpret_cast<ushort4*>(cb + (size_t)row * M + col0) = p;
                } else {
                    *reinterpret_cast<float4*>(C + (size_t)row * M + col0) = o;
                }
                if (C2) {
                    float4 q = make_float4(w0s * o.x, w0s * o.y, w0s * o.z, w0s * o.w);
                    *reinterpret_cast<float4*>(C2 + (size_t)row * M + col0) = q;
                }
            }
        }
    }

    if (STATS) {
        // per-thread fp32 partials over its RPT rows, LDS reduce, double atomics
        float s[4] = {0.f, 0.f, 0.f, 0.f}, q[4] = {0.f, 0.f, 0.f, 0.f};
#pragma unroll
        for (int r = 0; r < RPT; ++r) {
            int row = row0 + rg * RPT + r;
            if (row < n) {
#pragma unroll
                for (int c = 0; c < 4; ++c) {
                    float v = acc[r][c];
                    s[c] += v;
                    q[c] += v * v;
                }
            }
        }
        __syncthreads();                    // done with As
        float* sb = &As[0][0];              // [RG][CPB]
        float* qb = sb + RG * CPB;          // [RG][CPB]
#pragma unroll
        for (int c = 0; c < 4; ++c) {
            sb[rg * CPB + cg * 4 + c] = s[c];
            qb[rg * CPB + cg * 4 + c] = q[c];
        }
        __syncthreads();
        if (rg == 0 && col0 < M) {
#pragma unroll
            for (int c = 0; c < 4; ++c) {
                float ts = 0.f, tq = 0.f;
#pragma unroll
                for (int g2 = 0; g2 < RG; ++g2) {
                    ts += sb[g2 * CPB + cg * 4 + c];
                    tq += qb[g2 * CPB + cg * 4 + c];
                }
                atomicAdd(&stOut[col0 + c], (double)ts);
                atomicAdd(&stOut[M + col0 + c], (double)tq);
            }
        }
    }
}

// ---------------- BN column stats (sum, sumsq) in double ----------------
template<int M>
__global__ __launch_bounds__(256) void colstats(const float* __restrict__ Z,
                                                double* __restrict__ st, int n) {
    constexpr int RG = 256 / M;
    const int tid = threadIdx.x;
    const int c = tid % M, rg = tid / M;
    double s = 0.0, ss = 0.0;
    for (int row = blockIdx.x * RG + rg; row < n; row += gridDim.x * RG) {
        float v = Z[(size_t)row * M + c];
        s += v;
        ss += (double)v * (double)v;
    }
    __shared__ double sh[2][256];
    sh[0][tid] = s;
    sh[1][tid] = ss;
    __syncthreads();
    if (rg == 0) {
#pragma unroll
        for (int g = 1; g < RG; ++g) { s += sh[0][c + g * M]; ss += sh[1][c + g * M]; }
        atomicAdd(&st[c], s);
        atomicAdd(&st[M + c], ss);
    }
}

// ---------------- one propagation hop (CSR gather-sum, bf16 state) -----------
// Hop state rows are 64 bf16 = 128B. 8 lanes x 16B cover one row; 8 lane-groups
// process 8 neighbors per wave vmem instruction; x2 unrolled = 16 in flight.
// Accumulation fp32; nxt re-quantized bf16 RNE; oacc stays fp32.
__global__ __launch_bounds__(256) void propagate(
    const unsigned short* __restrict__ cur, unsigned short* __restrict__ nxt,
    float* __restrict__ oacc,
    const int* __restrict__ row_ptr, const int* __restrict__ col,
    const float* __restrict__ wts, int hop, int n) {
    const int node = blockIdx.x * 4 + (threadIdx.x >> 6);
    const int lane = threadIdx.x & 63;
    const int g = lane >> 3;      // neighbor slot 0..7
    const int l = lane & 7;       // feature oct: features l*8 .. l*8+7
    if (node >= n) return;
    const int beg = row_ptr[node], end = row_ptr[node + 1];
    float acc[8];
#pragma unroll
    for (int j = 0; j < 8; ++j) acc[j] = 0.f;

    int e = beg;
    for (; e + 16 <= end; e += 16) {
        int s0 = col[e + g];
        int s1 = col[e + g + 8];
        bf16x8 v0 = *reinterpret_cast<const bf16x8*>(cur + (size_t)s0 * DIM_P + l * 8);
        bf16x8 v1 = *reinterpret_cast<const bf16x8*>(cur + (size_t)s1 * DIM_P + l * 8);
#pragma unroll
        for (int j = 0; j < 8; ++j)
            acc[j] += bf2f((unsigned short)v0[j]) + bf2f((unsigned short)v1[j]);
    }
    if (e + 8 <= end) {
        int s = col[e + g];
        bf16x8 v = *reinterpret_cast<const bf16x8*>(cur + (size_t)s * DIM_P + l * 8);
#pragma unroll
        for (int j = 0; j < 8; ++j) acc[j] += bf2f((unsigned short)v[j]);
        e += 8;
    }
    if (e + g < end) {
        int s = col[e + g];
        bf16x8 v = *reinterpret_cast<const bf16x8*>(cur + (size_t)s * DIM_P + l * 8);
#pragma unroll
        for (int j = 0; j < 8; ++j) acc[j] += bf2f((unsigned short)v[j]);
    }

    // reduce across the 8 lane-groups (offsets 8,16,32 keep l fixed)
#pragma unroll
    for (int off = 8; off < 64; off <<= 1) {
#pragma unroll
        for (int j = 0; j < 8; ++j) acc[j] += __shfl_xor(acc[j], off, 64);
    }

    if (g == 0) {
        const size_t o = (size_t)node * DIM_P + l * 8;
        if (nxt) {
            bf16x8 ov;
#pragma unroll
            for (int j = 0; j < 8; ++j) ov[j] = (short)f2bf_rne(acc[j]);
            *reinterpret_cast<bf16x8*>(nxt + o) = ov;
        }
        const float w = wts[hop];
        float* op = oacc + o;
        float4 t0 = *reinterpret_cast<const float4*>(op);
        float4 t1 = *reinterpret_cast<const float4*>(op + 4);
        t0.x = fmaf(w, acc[0], t0.x); t0.y = fmaf(w, acc[1], t0.y);
        t0.z = fmaf(w, acc[2], t0.z); t0.w = fmaf(w, acc[3], t0.w);
        t1.x = fmaf(w, acc[4], t1.x); t1.y = fmaf(w, acc[5], t1.y);
        t1.z = fmaf(w, acc[6], t1.z); t1.w = fmaf(w, acc[7], t1.w);
        *reinterpret_cast<float4*>(op) = t0;
        *reinterpret_cast<float4*>(op + 4) = t1;
    }
}

// ------- bn3(inline finalize) + relu + bf16 convert, once: ABF[row][k] -------
__global__ void bn3_relu_bf16(const float* __restrict__ Z, const double* __restrict__ st3,
                              const float* __restrict__ g3, const float* __restrict__ be3,
                              unsigned short* __restrict__ O) {
    __shared__ float sc[DIM_P], sh[DIM_P];
    if (threadIdx.x < DIM_P) {
        int c = threadIdx.x;
        double m = st3[c] / N_NODES;
        double v = st3[DIM_P + c] / N_NODES - m * m;
        float scale = g3[c] * rsqrtf((float)v + BN_EPS);
        sc[c] = scale;
        sh[c] = be3[c] - (float)m * scale;
    }
    __syncthreads();
    const int total8 = N_NODES * DIM_P / 8;
    int i = blockIdx.x * blockDim.x + threadIdx.x;
    if (i >= total8) return;
    int base = i * 8;
    int c = base & (DIM_P - 1);
    float4 z0 = *reinterpret_cast<const float4*>(Z + base);
    float4 z1 = *reinterpret_cast<const float4*>(Z + base + 4);
    float4 s0 = *reinterpret_cast<const float4*>(&sc[c]);
    float4 s1 = *reinterpret_cast<const float4*>(&sc[c + 4]);
    float4 h0 = *reinterpret_cast<const float4*>(&sh[c]);
    float4 h1 = *reinterpret_cast<const float4*>(&sh[c + 4]);
    bf16x8 o;
    o[0] = (short)f2bf_rne(fmaxf(z0.x * s0.x + h0.x, 0.f));
    o[1] = (short)f2bf_rne(fmaxf(z0.y * s0.y + h0.y, 0.f));
    o[2] = (short)f2bf_rne(fmaxf(z0.z * s0.z + h0.z, 0.f));
    o[3] = (short)f2bf_rne(fmaxf(z0.w * s0.w + h0.w, 0.f));
    o[4] = (short)f2bf_rne(fmaxf(z1.x * s1.x + h1.x, 0.f));
    o[5] = (short)f2bf_rne(fmaxf(z1.y * s1.y + h1.y, 0.f));
    o[6] = (short)f2bf_rne(fmaxf(z1.z * s1.z + h1.z, 0.f));
    o[7] = (short)f2bf_rne(fmaxf(z1.w * s1.w + h1.w, 0.f));
    *reinterpret_cast<bf16x8*>(O + base) = o;
}

// ---------------- final GEMM via MFMA: out = ABF @ Wout + bout ----------------
// A-operand = Wout columns (register-resident across row loop), B = node rows.
// Each lane stores float4 of 4 consecutive output columns.
__global__ __launch_bounds__(256, 4) void out_gemm_mfma(
    const unsigned short* __restrict__ ABF, const unsigned short* __restrict__ WT,
    const float* __restrict__ bout, float* __restrict__ out) {
    const int wave = threadIdx.x >> 6;
    const int lane = threadIdx.x & 63;
    const int m    = lane & 15;       // A: out-col within tile; B/D: out-row
    const int quad = lane >> 4;
    const int kb   = quad * 8;
    const int c0   = blockIdx.y * 256 + wave * 64;

    bf16x8 afrag[4][2];
    float4 bias[4];
#pragma unroll
    for (int t = 0; t < 4; ++t) {
        const unsigned short* wrow = WT + (size_t)(c0 + t * 16 + m) * DIM_P;
        afrag[t][0] = *reinterpret_cast<const bf16x8*>(wrow + kb);
        afrag[t][1] = *reinterpret_cast<const bf16x8*>(wrow + 32 + kb);
        int cc = c0 + t * 16 + quad * 4;
        bias[t] = (cc < DIM_OUT) ? *reinterpret_cast<const float4*>(bout + cc)
                                 : make_float4(0.f, 0.f, 0.f, 0.f);
    }

    const int NT = N_NODES / 16;  // 3125 row tiles
    for (int rt = blockIdx.x; rt < NT; rt += gridDim.x) {
        const int row = rt * 16 + m;
        const unsigned short* arow = ABF + (size_t)row * DIM_P;
        bf16x8 bfrag0 = *reinterpret_cast<const bf16x8*>(arow + kb);
        bf16x8 bfrag1 = *reinterpret_cast<const bf16x8*>(arow + 32 + kb);
        float* orow = out + (size_t)row * DIM_OUT;
#pragma unroll
        for (int t = 0; t < 4; ++t) {
            floatx4 acc = {0.f, 0.f, 0.f, 0.f};
            acc = __builtin_amdgcn_mfma_f32_16x16x32_bf16(afrag[t][0], bfrag0, acc, 0, 0, 0);
            acc = __builtin_amdgcn_mfma_f32_16x16x32_bf16(afrag[t][1], bfrag1, acc, 0, 0, 0);
            int cc = c0 + t * 16 + quad * 4;
            if (cc < DIM_OUT) {
                float4 o = make_float4(acc[0] + bias[t].x, acc[1] + bias[t].y,
                                       acc[2] + bias[t].z, acc[3] + bias[t].w);
                *reinterpret_cast<float4*>(orow + cc) = o;
            }
        }
    }
}

// ---------------- launch ----------------
extern "C" void kernel_launch(void* const* d_in, const int* in_sizes, int n_in,
                              void* d_out, int out_size, void* d_ws, size_t ws_size,
                              hipStream_t stream) {
    const float* x    = (const float*)d_in[0];
    const int*   ei   = (const int*)  d_in[1];
    const float* W1   = (const float*)d_in[2];
    const float* g1   = (const float*)d_in[4];
    const float* be1  = (const float*)d_in[5];
    const float* W2   = (const float*)d_in[6];
    const float* g2   = (const float*)d_in[8];
    const float* be2  = (const float*)d_in[9];
    const float* att  = (const float*)d_in[10];
    const float* W3   = (const float*)d_in[11];
    const float* g3   = (const float*)d_in[13];
    const float* be3  = (const float*)d_in[14];
    const float* Wout = (const float*)d_in[15];
    const float* bout = (const float*)d_in[16];
    float* out = (float*)d_out;

    char* base = (char*)d_ws;
    size_t off = 0;
    auto alloc = [&](size_t bytes) -> void* {
        void* r = base + off;
        off += (bytes + 255) & ~(size_t)255;
        return r;
    };
    float*  f0      = (float*) alloc((size_t)N_NODES * DIM_H * 4); // z1
    float*  f1      = (float*) alloc((size_t)N_NODES * DIM_H * 4); // z2
    unsigned short* yb = (unsigned short*)alloc((size_t)N_NODES * DIM_P * 2); // bf16 hop ping
    unsigned short* tb = (unsigned short*)alloc((size_t)N_NODES * DIM_P * 2); // bf16 hop pong
    float*  oa      = (float*) alloc((size_t)N_NODES * DIM_P * 4); // fp32 weighted acc
    double* st      = (double*)alloc(640 * 8);
    float*  wts     = (float*) alloc(16 * 4);
    int*    row_ptr = (int*)   alloc((size_t)(N_NODES + 1) * 4);
    int*    deg     = (int*)   alloc((size_t)N_NODES * 4);   // degree -> cursor
    int*    col     = (int*)   alloc((size_t)N_EDGES * 4);
    int*    bsums   = (int*)   alloc(64 * 4);
    unsigned short* WT  = (unsigned short*)alloc((size_t)OUT_PAD * DIM_P * 2);
    unsigned short* ABF = (unsigned short*)alloc((size_t)N_NODES * DIM_P * 2);

    const int* src = ei;
    const int* dst = ei + N_EDGES;
    double* st1 = st;   double* st2 = st + 256; double* st3 = st + 512;

    // 1 dispatch: softmax + Wout prep + zero stats/deg
    init_all<<<256, 256, 0, stream>>>(att, wts, Wout, WT, st, deg);

    // CSR by destination (4 dispatches; bsums scan folded into scan_finish)
    count_deg<<<ceil_div(N_EDGES, 256), 256, 0, stream>>>(dst, deg, N_EDGES);
    const int NB = ceil_div(N_NODES, 1024);
    scan_local<<<NB, 1024, 0, stream>>>(deg, row_ptr, bsums, N_NODES);
    scan_finish<<<ceil_div(N_NODES, 256), 256, 0, stream>>>(row_ptr, deg, bsums,
                                                            N_NODES, NB);
    fill_csr<<<ceil_div(N_EDGES, 256), 256, 0, stream>>>(src, dst, deg, col, N_EDGES);

    const int RB = ceil_div(N_NODES, 64);

    // layer 1: z1 = x@W1, stats fused (b1 cancels in BN)
    gemm_fused<128, 128, true, false><<<dim3(RB, 1), 256, 0, stream>>>(
        x, nullptr, nullptr, nullptr,
        nullptr, nullptr, nullptr, nullptr,
        W1, f0, nullptr, nullptr, st1, N_NODES, DIM_H);

    // layer 2: z2 = relu(bn1(z1))@W2, bn1 finalized in-kernel, stats fused
    gemm_fused<128, 128, true, false><<<dim3(RB, 1), 256, 0, stream>>>(
        f0, st1, g1, be1,
        nullptr, nullptr, nullptr, nullptr,
        W2, f1, nullptr, nullptr, st2, N_NODES, DIM_H);

    // layer 3 input: h2 = relu(bn2(z2)) + relu(bn1(z1)); y = h2@W3.
    // C -> yb (bf16 hop state), C2 -> oa = w0*y (fp32, unquantized hop-0 term)
    gemm_fused<128, 64, false, true><<<dim3(RB, 1), 256, 0, stream>>>(
        f1, st2, g2, be2,
        f0, st1, g1, be1,
        W3, (float*)yb, oa, wts, nullptr, N_NODES, DIM_P);

    // 10 hops, bf16 state (half the gather bytes of fp32), launch per hop
    {
        unsigned short* cur = yb;
        unsigned short* nxt = tb;
        for (int hop = 1; hop <= KHOPS; ++hop) {
            propagate<<<ceil_div(N_NODES, 4), 256, 0, stream>>>(
                cur, (hop == KHOPS) ? nullptr : nxt, oa, row_ptr, col, wts, hop, N_NODES);
            unsigned short* t = cur; cur = nxt; nxt = t;
        }
    }

    // layer 3 BN stats (b3 cancels); bn3 finalize folded into the bf16 pass
    colstats<64><<<256, 256, 0, stream>>>(oa, st3, N_NODES);
    bn3_relu_bf16<<<ceil_div(N_NODES * DIM_P / 8, 256), 256, 0, stream>>>(
        oa, st3, g3, be3, ABF);

    // output: out = ABF @ Wout + bout   (bf16 MFMA, column-persistent waves)
    out_gemm_mfma<<<dim3(512, 4), 256, 0, stream>>>(ABF, WT, bout, out);
}

// Round 10
// 759.910 us; speedup vs baseline: 1.1482x; 1.1482x over previous
//
#include <hip/hip_runtime.h>
#include <cstdint>
#include <cstddef>

#define N_NODES 50000
#define N_EDGES 800000
#define DIM_H   128
#define DIM_P   64     // propagation width after commuting W3
#define DIM_OUT 1000
#define OUT_PAD 1024   // padded col count for MFMA tiles
#define KHOPS   10
#define BN_EPS  1e-5f

static inline int ceil_div(int a, int b) { return (a + b - 1) / b; }

typedef short  bf16x8  __attribute__((ext_vector_type(8)));
typedef float  floatx4 __attribute__((ext_vector_type(4)));

__device__ __forceinline__ unsigned short f2bf_rne(float v) {
    unsigned int u = __float_as_uint(v);
    return (unsigned short)((u + 0x7fffu + ((u >> 16) & 1u)) >> 16);
}
__device__ __forceinline__ float bf2f(unsigned short u) {
    return __uint_as_float((unsigned int)u << 16);
}

// ------- init: softmax(att) + Wout transpose/bf16 + zero st/deg, one kernel ---
__global__ void init_all(const float* __restrict__ att, float* __restrict__ w,
                         const float* __restrict__ Wout, unsigned short* __restrict__ WT,
                         double* __restrict__ st, int* __restrict__ deg) {
    const int gid = blockIdx.x * blockDim.x + threadIdx.x;
    const int stride = gridDim.x * blockDim.x;
    if (gid == 0) {
        float mx = att[0];
        for (int i = 1; i < KHOPS + 1; ++i) mx = fmaxf(mx, att[i]);
        float e[KHOPS + 1];
        float s = 0.f;
        for (int i = 0; i < KHOPS + 1; ++i) { e[i] = expf(att[i] - mx); s += e[i]; }
        for (int i = 0; i < KHOPS + 1; ++i) w[i] = e[i] / s;
    }
    for (int i = gid; i < 640; i += stride) st[i] = 0.0;
    for (int i = gid; i < N_NODES; i += stride) deg[i] = 0;
    for (int i = gid; i < OUT_PAD * DIM_P; i += stride) {
        int c = i >> 6, k = i & 63;
        WT[i] = (c < DIM_OUT) ? f2bf_rne(Wout[(size_t)k * DIM_OUT + c]) : (unsigned short)0;
    }
}

// ---------------- CSR build ----------------
__global__ void count_deg(const int* __restrict__ dst, int* __restrict__ deg, int ne) {
    int i = blockIdx.x * blockDim.x + threadIdx.x;
    if (i < ne) atomicAdd(&deg[dst[i]], 1);
}

// local inclusive scan per 1024-block (shuffle-based, 3 barriers)
__global__ __launch_bounds__(1024) void scan_local(const int* __restrict__ deg,
                                                   int* __restrict__ row_ptr,
                                                   int* __restrict__ bsums, int n) {
    __shared__ int wsum[16];
    const int i = blockIdx.x * 1024 + threadIdx.x;
    const int lane = threadIdx.x & 63, w = threadIdx.x >> 6;
    int v = (i < n) ? deg[i] : 0;
    int s = v;
#pragma unroll
    for (int d = 1; d < 64; d <<= 1) {
        int t = __shfl_up(s, d, 64);
        if (lane >= d) s += t;
    }
    if (lane == 63) wsum[w] = s;
    __syncthreads();
    if (w == 0) {
        int x = (lane < 16) ? wsum[lane] : 0;
#pragma unroll
        for (int d = 1; d < 16; d <<= 1) {
            int t = __shfl_up(x, d, 64);
            if (lane >= d) x += t;
        }
        if (lane < 16) wsum[lane] = x;
    }
    __syncthreads();
    int incl = s + ((w > 0) ? wsum[w - 1] : 0);
    if (i < n) row_ptr[i + 1] = incl;
    if (threadIdx.x == 1023) bsums[blockIdx.x] = incl;
}

// add block offsets (block-sum exclusive scan redone per block in wave 0);
// also derive fill-cursor (exclusive start) in-place in deg
__global__ void scan_finish(int* __restrict__ row_ptr, int* __restrict__ deg,
                            const int* __restrict__ bsums, int n, int nb) {
    __shared__ int boff[64];
    if (threadIdx.x < 64) {
        int lane = threadIdx.x;
        int v = (lane < nb) ? bsums[lane] : 0;
        int s = v;
#pragma unroll
        for (int d = 1; d < 64; d <<= 1) {
            int t = __shfl_up(s, d, 64);
            if (lane >= d) s += t;
        }
        boff[lane] = s - v;   // exclusive prefix
    }
    __syncthreads();
    int i = blockIdx.x * blockDim.x + threadIdx.x;
    if (i < n) {
        int incl = row_ptr[i + 1] + boff[i >> 10];
        row_ptr[i + 1] = incl;
        deg[i] = incl - deg[i];   // cursor = exclusive prefix
    }
    if (i == 0) row_ptr[0] = 0;
}

__global__ void fill_csr(const int* __restrict__ src, const int* __restrict__ dst,
                         int* __restrict__ cursor, int* __restrict__ col, int ne) {
    int i = blockIdx.x * blockDim.x + threadIdx.x;
    if (i < ne) {
        int d = dst[i];
        int pos = atomicAdd(&cursor[d], 1);
        col[pos] = src[i];
    }
}

// ---------------- fused GEMM: C[n,M] = act(A) @ W -------------------
// act(A) row = relu(A*sc+sh) [if stA] + relu(A2*sc2+sh2) [if A2]; BN scale/shift
// computed IN-KERNEL from double stats (st, gamma, beta) — replaces bn_finalize.
// OBF: C stored as bf16 (propagation hop state). NO fused stats (atomic
// contention on the GEMM critical path cost +73us in R9 — use separate colstats).
template<int KD, int CPB, bool OBF>
__global__ __launch_bounds__(256) void gemm_fused(
    const float* __restrict__ A,  const double* __restrict__ stA,
    const float* __restrict__ gA, const float* __restrict__ beA,
    const float* __restrict__ A2, const double* __restrict__ stA2,
    const float* __restrict__ gA2, const float* __restrict__ beA2,
    const float* __restrict__ W,
    float* __restrict__ C, int n, int M) {
    constexpr int CG  = CPB / 4;     // col groups per block
    constexpr int RG  = 256 / CG;    // row groups
    constexpr int RPT = 64 / RG;     // rows per thread
    __shared__ float As[64][KD + 4];
    __shared__ float scA_l[2][KD];
    __shared__ float scA2_l[2][KD];

    const int tid  = threadIdx.x;
    const int cg   = tid % CG;
    const int rg   = tid / CG;
    const int row0 = blockIdx.x * 64;
    const int col0 = blockIdx.y * CPB + cg * 4;

    // inline bn_finalize (identical math to the old separate kernel)
    if (stA && tid < KD) {
        double m = stA[tid] / n;
        double v = stA[KD + tid] / n - m * m;
        float scale = gA[tid] * rsqrtf((float)v + BN_EPS);
        scA_l[0][tid] = scale;
        scA_l[1][tid] = beA[tid] - (float)m * scale;
    }
    if (A2 && tid < KD) {
        double m = stA2[tid] / n;
        double v = stA2[KD + tid] / n - m * m;
        float scale = gA2[tid] * rsqrtf((float)v + BN_EPS);
        scA2_l[0][tid] = scale;
        scA2_l[1][tid] = beA2[tid] - (float)m * scale;
    }
    if (stA || A2) __syncthreads();

    constexpr int VECS = 64 * KD / 4;
    for (int i = tid; i < VECS; i += 256) {
        int r  = i / (KD / 4);
        int k4 = (i % (KD / 4)) * 4;
        float4 v = make_float4(0.f, 0.f, 0.f, 0.f);
        int row = row0 + r;
        if (row < n) {
            v = *reinterpret_cast<const float4*>(A + (size_t)row * KD + k4);
            if (stA) {
                float4 sc = *reinterpret_cast<const float4*>(&scA_l[0][k4]);
                float4 sh = *reinterpret_cast<const float4*>(&scA_l[1][k4]);
                v.x = fmaxf(v.x * sc.x + sh.x, 0.f);
                v.y = fmaxf(v.y * sc.y + sh.y, 0.f);
                v.z = fmaxf(v.z * sc.z + sh.z, 0.f);
                v.w = fmaxf(v.w * sc.w + sh.w, 0.f);
            }
            if (A2) {
                float4 u  = *reinterpret_cast<const float4*>(A2 + (size_t)row * KD + k4);
                float4 sc = *reinterpret_cast<const float4*>(&scA2_l[0][k4]);
                float4 sh = *reinterpret_cast<const float4*>(&scA2_l[1][k4]);
                v.x += fmaxf(u.x * sc.x + sh.x, 0.f);
                v.y += fmaxf(u.y * sc.y + sh.y, 0.f);
                v.z += fmaxf(u.z * sc.z + sh.z, 0.f);
                v.w += fmaxf(u.w * sc.w + sh.w, 0.f);
            }
        }
        *reinterpret_cast<float4*>(&As[r][k4]) = v;
    }
    __syncthreads();

    if (col0 >= M) return;

    float acc[RPT][4];
#pragma unroll
    for (int r = 0; r < RPT; ++r)
#pragma unroll
        for (int c = 0; c < 4; ++c) acc[r][c] = 0.f;

    for (int k4 = 0; k4 < KD; k4 += 4) {
        float4 w0 = *reinterpret_cast<const float4*>(W + (size_t)(k4 + 0) * M + col0);
        float4 w1 = *reinterpret_cast<const float4*>(W + (size_t)(k4 + 1) * M + col0);
        float4 w2 = *reinterpret_cast<const float4*>(W + (size_t)(k4 + 2) * M + col0);
        float4 w3 = *reinterpret_cast<const float4*>(W + (size_t)(k4 + 3) * M + col0);
#pragma unroll
        for (int r = 0; r < RPT; ++r) {
            float4 a = *reinterpret_cast<const float4*>(&As[rg * RPT + r][k4]);
            acc[r][0] += a.x * w0.x + a.y * w1.x + a.z * w2.x + a.w * w3.x;
            acc[r][1] += a.x * w0.y + a.y * w1.y + a.z * w2.y + a.w * w3.y;
            acc[r][2] += a.x * w0.z + a.y * w1.z + a.z * w2.z + a.w * w3.z;
            acc[r][3] += a.x * w0.w + a.y * w1.w + a.z * w2.w + a.w * w3.w;
        }
    }

#pragma unroll
    for (int r = 0; r < RPT; ++r) {
        int row = row0 + rg * RPT + r;
        if (row < n) {
            float4 o = make_float4(acc[r][0], acc[r][1], acc[r][2], acc[r][3]);
            if (OBF) {
                unsigned short* cb = reinterpret_cast<unsigned short*>(C);
                ushort4 p;
                p.x = f2bf_rne(o.x); p.y = f2bf_rne(o.y);
                p.z = f2bf_rne(o.z); p.w = f2bf_rne(o.w);
                *reinterpret_cast<ushort4*>(cb + (size_t)row * M + col0) = p;
            } else {
                *reinterpret_cast<float4*>(C + (size_t)row * M + col0) = o;
            }
        }
    }
}

// ---------------- BN column stats (sum, sumsq) in double ----------------
template<int M>
__global__ __launch_bounds__(256) void colstats(const float* __restrict__ Z,
                                                double* __restrict__ st, int n) {
    constexpr int RG = 256 / M;
    const int tid = threadIdx.x;
    const int c = tid % M, rg = tid / M;
    double s = 0.0, ss = 0.0;
    for (int row = blockIdx.x * RG + rg; row < n; row += gridDim.x * RG) {
        float v = Z[(size_t)row * M + c];
        s += v;
        ss += (double)v * (double)v;
    }
    __shared__ double sh[2][256];
    sh[0][tid] = s;
    sh[1][tid] = ss;
    __syncthreads();
    if (rg == 0) {
#pragma unroll
        for (int g = 1; g < RG; ++g) { s += sh[0][c + g * M]; ss += sh[1][c + g * M]; }
        atomicAdd(&st[c], s);
        atomicAdd(&st[M + c], ss);
    }
}

// ---------------- one propagation hop (CSR gather-sum, bf16 state) -----------
// Pure gather: no oacc rmw (weighted sum deferred to wsum_stats). Hop state
// rows are 64 bf16 = 128B. 8 lanes x 16B cover one row; 8 lane-groups process
// 8 neighbors per wave vmem instruction; x2 unrolled = 16 in flight.
__global__ __launch_bounds__(256) void propagate(
    const unsigned short* __restrict__ cur, unsigned short* __restrict__ nxt,
    const int* __restrict__ row_ptr, const int* __restrict__ col, int n) {
    const int node = blockIdx.x * 4 + (threadIdx.x >> 6);
    const int lane = threadIdx.x & 63;
    const int g = lane >> 3;      // neighbor slot 0..7
    const int l = lane & 7;       // feature oct: features l*8 .. l*8+7
    if (node >= n) return;
    const int beg = row_ptr[node], end = row_ptr[node + 1];
    float acc[8];
#pragma unroll
    for (int j = 0; j < 8; ++j) acc[j] = 0.f;

    int e = beg;
    for (; e + 16 <= end; e += 16) {
        int s0 = col[e + g];
        int s1 = col[e + g + 8];
        bf16x8 v0 = *reinterpret_cast<const bf16x8*>(cur + (size_t)s0 * DIM_P + l * 8);
        bf16x8 v1 = *reinterpret_cast<const bf16x8*>(cur + (size_t)s1 * DIM_P + l * 8);
#pragma unroll
        for (int j = 0; j < 8; ++j)
            acc[j] += bf2f((unsigned short)v0[j]) + bf2f((unsigned short)v1[j]);
    }
    if (e + 8 <= end) {
        int s = col[e + g];
        bf16x8 v = *reinterpret_cast<const bf16x8*>(cur + (size_t)s * DIM_P + l * 8);
#pragma unroll
        for (int j = 0; j < 8; ++j) acc[j] += bf2f((unsigned short)v[j]);
        e += 8;
    }
    if (e + g < end) {
        int s = col[e + g];
        bf16x8 v = *reinterpret_cast<const bf16x8*>(cur + (size_t)s * DIM_P + l * 8);
#pragma unroll
        for (int j = 0; j < 8; ++j) acc[j] += bf2f((unsigned short)v[j]);
    }

    // reduce across the 8 lane-groups (offsets 8,16,32 keep l fixed)
#pragma unroll
    for (int off = 8; off < 64; off <<= 1) {
#pragma unroll
        for (int j = 0; j < 8; ++j) acc[j] += __shfl_xor(acc[j], off, 64);
    }

    if (g == 0) {
        bf16x8 ov;
#pragma unroll
        for (int j = 0; j < 8; ++j) ov[j] = (short)f2bf_rne(acc[j]);
        *reinterpret_cast<bf16x8*>(nxt + (size_t)node * DIM_P + l * 8) = ov;
    }
}

// ------- weighted hop sum + bn3 stats: oa = sum_i w[i]*hs[i]; st3 += stats ----
// hs: [KHOPS+1][n*64] bf16 chain (hs[0]=y). Same summation order as the old
// per-hop oa accumulation; colstats-pattern atomics (256 blocks per address).
__global__ __launch_bounds__(256) void wsum_stats(
    const unsigned short* __restrict__ hs, const float* __restrict__ wts,
    float* __restrict__ oa, double* __restrict__ st, int n) {
    const int tid = threadIdx.x;
    const int c = tid & 63, rg = tid >> 6;   // 4 row groups
    float w[KHOPS + 1];
#pragma unroll
    for (int i = 0; i < KHOPS + 1; ++i) w[i] = wts[i];
    const size_t stride = (size_t)n * DIM_P;
    double s = 0.0, ss = 0.0;
    for (int row = blockIdx.x * 4 + rg; row < n; row += gridDim.x * 4) {
        const size_t idx = (size_t)row * DIM_P + c;
        float val = 0.f;
#pragma unroll
        for (int i = 0; i < KHOPS + 1; ++i)
            val += w[i] * bf2f(hs[idx + (size_t)i * stride]);
        oa[idx] = val;
        s += val;
        ss += (double)val * (double)val;
    }
    __shared__ double sh[2][256];
    sh[0][tid] = s;
    sh[1][tid] = ss;
    __syncthreads();
    if (rg == 0) {
#pragma unroll
        for (int g2 = 1; g2 < 4; ++g2) { s += sh[0][c + g2 * 64]; ss += sh[1][c + g2 * 64]; }
        atomicAdd(&st[c], s);
        atomicAdd(&st[64 + c], ss);
    }
}

// ------- bn3(inline finalize) + relu + bf16 convert, once: ABF[row][k] -------
__global__ void bn3_relu_bf16(const float* __restrict__ Z, const double* __restrict__ st3,
                              const float* __restrict__ g3, const float* __restrict__ be3,
                              unsigned short* __restrict__ O) {
    __shared__ float sc[DIM_P], sh[DIM_P];
    if (threadIdx.x < DIM_P) {
        int c = threadIdx.x;
        double m = st3[c] / N_NODES;
        double v = st3[DIM_P + c] / N_NODES - m * m;
        float scale = g3[c] * rsqrtf((float)v + BN_EPS);
        sc[c] = scale;
        sh[c] = be3[c] - (float)m * scale;
    }
    __syncthreads();
    const int total8 = N_NODES * DIM_P / 8;
    int i = blockIdx.x * blockDim.x + threadIdx.x;
    if (i >= total8) return;
    int base = i * 8;
    int c = base & (DIM_P - 1);
    float4 z0 = *reinterpret_cast<const float4*>(Z + base);
    float4 z1 = *reinterpret_cast<const float4*>(Z + base + 4);
    float4 s0 = *reinterpret_cast<const float4*>(&sc[c]);
    float4 s1 = *reinterpret_cast<const float4*>(&sc[c + 4]);
    float4 h0 = *reinterpret_cast<const float4*>(&sh[c]);
    float4 h1 = *reinterpret_cast<const float4*>(&sh[c + 4]);
    bf16x8 o;
    o[0] = (short)f2bf_rne(fmaxf(z0.x * s0.x + h0.x, 0.f));
    o[1] = (short)f2bf_rne(fmaxf(z0.y * s0.y + h0.y, 0.f));
    o[2] = (short)f2bf_rne(fmaxf(z0.z * s0.z + h0.z, 0.f));
    o[3] = (short)f2bf_rne(fmaxf(z0.w * s0.w + h0.w, 0.f));
    o[4] = (short)f2bf_rne(fmaxf(z1.x * s1.x + h1.x, 0.f));
    o[5] = (short)f2bf_rne(fmaxf(z1.y * s1.y + h1.y, 0.f));
    o[6] = (short)f2bf_rne(fmaxf(z1.z * s1.z + h1.z, 0.f));
    o[7] = (short)f2bf_rne(fmaxf(z1.w * s1.w + h1.w, 0.f));
    *reinterpret_cast<bf16x8*>(O + base) = o;
}

// ---------------- final GEMM via MFMA: out = ABF @ Wout + bout ----------------
// A-operand = Wout columns (register-resident across row loop), B = node rows.
// Each lane stores float4 of 4 consecutive output columns.
__global__ __launch_bounds__(256, 4) void out_gemm_mfma(
    const unsigned short* __restrict__ ABF, const unsigned short* __restrict__ WT,
    const float* __restrict__ bout, float* __restrict__ out) {
    const int wave = threadIdx.x >> 6;
    const int lane = threadIdx.x & 63;
    const int m    = lane & 15;       // A: out-col within tile; B/D: out-row
    const int quad = lane >> 4;
    const int kb   = quad * 8;
    const int c0   = blockIdx.y * 256 + wave * 64;

    bf16x8 afrag[4][2];
    float4 bias[4];
#pragma unroll
    for (int t = 0; t < 4; ++t) {
        const unsigned short* wrow = WT + (size_t)(c0 + t * 16 + m) * DIM_P;
        afrag[t][0] = *reinterpret_cast<const bf16x8*>(wrow + kb);
        afrag[t][1] = *reinterpret_cast<const bf16x8*>(wrow + 32 + kb);
        int cc = c0 + t * 16 + quad * 4;
        bias[t] = (cc < DIM_OUT) ? *reinterpret_cast<const float4*>(bout + cc)
                                 : make_float4(0.f, 0.f, 0.f, 0.f);
    }

    const int NT = N_NODES / 16;  // 3125 row tiles
    for (int rt = blockIdx.x; rt < NT; rt += gridDim.x) {
        const int row = rt * 16 + m;
        const unsigned short* arow = ABF + (size_t)row * DIM_P;
        bf16x8 bfrag0 = *reinterpret_cast<const bf16x8*>(arow + kb);
        bf16x8 bfrag1 = *reinterpret_cast<const bf16x8*>(arow + 32 + kb);
        float* orow = out + (size_t)row * DIM_OUT;
#pragma unroll
        for (int t = 0; t < 4; ++t) {
            floatx4 acc = {0.f, 0.f, 0.f, 0.f};
            acc = __builtin_amdgcn_mfma_f32_16x16x32_bf16(afrag[t][0], bfrag0, acc, 0, 0, 0);
            acc = __builtin_amdgcn_mfma_f32_16x16x32_bf16(afrag[t][1], bfrag1, acc, 0, 0, 0);
            int cc = c0 + t * 16 + quad * 4;
            if (cc < DIM_OUT) {
                float4 o = make_float4(acc[0] + bias[t].x, acc[1] + bias[t].y,
                                       acc[2] + bias[t].z, acc[3] + bias[t].w);
                *reinterpret_cast<float4*>(orow + cc) = o;
            }
        }
    }
}

// ---------------- launch ----------------
extern "C" void kernel_launch(void* const* d_in, const int* in_sizes, int n_in,
                              void* d_out, int out_size, void* d_ws, size_t ws_size,
                              hipStream_t stream) {
    const float* x    = (const float*)d_in[0];
    const int*   ei   = (const int*)  d_in[1];
    const float* W1   = (const float*)d_in[2];
    const float* g1   = (const float*)d_in[4];
    const float* be1  = (const float*)d_in[5];
    const float* W2   = (const float*)d_in[6];
    const float* g2   = (const float*)d_in[8];
    const float* be2  = (const float*)d_in[9];
    const float* att  = (const float*)d_in[10];
    const float* W3   = (const float*)d_in[11];
    const float* g3   = (const float*)d_in[13];
    const float* be3  = (const float*)d_in[14];
    const float* Wout = (const float*)d_in[15];
    const float* bout = (const float*)d_in[16];
    float* out = (float*)d_out;

    char* base = (char*)d_ws;
    size_t off = 0;
    auto alloc = [&](size_t bytes) -> void* {
        void* r = base + off;
        off += (bytes + 255) & ~(size_t)255;
        return r;
    };
    const size_t SSTRIDE = (size_t)N_NODES * DIM_P;   // elements per hop state
    float*  f0      = (float*) alloc((size_t)N_NODES * DIM_H * 4); // z1
    float*  f1      = (float*) alloc((size_t)N_NODES * DIM_H * 4); // z2
    unsigned short* hs = (unsigned short*)alloc((size_t)(KHOPS + 1) * SSTRIDE * 2);
    float*  oa      = (float*) alloc(SSTRIDE * 4);    // fp32 weighted acc
    double* st      = (double*)alloc(640 * 8);
    float*  wts     = (float*) alloc(16 * 4);
    int*    row_ptr = (int*)   alloc((size_t)(N_NODES + 1) * 4);
    int*    deg     = (int*)   alloc((size_t)N_NODES * 4);   // degree -> cursor
    int*    col     = (int*)   alloc((size_t)N_EDGES * 4);
    int*    bsums   = (int*)   alloc(64 * 4);
    unsigned short* WT  = (unsigned short*)alloc((size_t)OUT_PAD * DIM_P * 2);
    unsigned short* ABF = (unsigned short*)alloc(SSTRIDE * 2);

    const int* src = ei;
    const int* dst = ei + N_EDGES;
    double* st1 = st;   double* st2 = st + 256; double* st3 = st + 512;

    // 1 dispatch: softmax + Wout prep + zero stats/deg
    init_all<<<256, 256, 0, stream>>>(att, wts, Wout, WT, st, deg);

    // CSR by destination (4 dispatches; bsums scan folded into scan_finish)
    count_deg<<<ceil_div(N_EDGES, 256), 256, 0, stream>>>(dst, deg, N_EDGES);
    const int NB = ceil_div(N_NODES, 1024);
    scan_local<<<NB, 1024, 0, stream>>>(deg, row_ptr, bsums, N_NODES);
    scan_finish<<<ceil_div(N_NODES, 256), 256, 0, stream>>>(row_ptr, deg, bsums,
                                                            N_NODES, NB);
    fill_csr<<<ceil_div(N_EDGES, 256), 256, 0, stream>>>(src, dst, deg, col, N_EDGES);

    const int RB = ceil_div(N_NODES, 64);

    // layer 1: z1 = x@W1 (b1 cancels in BN); stats via separate colstats
    gemm_fused<128, 128, false><<<dim3(RB, 1), 256, 0, stream>>>(
        x, nullptr, nullptr, nullptr,
        nullptr, nullptr, nullptr, nullptr,
        W1, f0, N_NODES, DIM_H);
    colstats<128><<<256, 256, 0, stream>>>(f0, st1, N_NODES);

    // layer 2: z2 = relu(bn1(z1))@W2, bn1 finalized in-kernel
    gemm_fused<128, 128, false><<<dim3(RB, 1), 256, 0, stream>>>(
        f0, st1, g1, be1,
        nullptr, nullptr, nullptr, nullptr,
        W2, f1, N_NODES, DIM_H);
    colstats<128><<<256, 256, 0, stream>>>(f1, st2, N_NODES);

    // layer 3 input: h2 = relu(bn2(z2)) + relu(bn1(z1)); y = h2@W3 -> hs[0] bf16
    gemm_fused<128, 64, true><<<dim3(RB, 1), 256, 0, stream>>>(
        f1, st2, g2, be2,
        f0, st1, g1, be1,
        W3, (float*)hs, N_NODES, DIM_P);

    // 10 hops over the bf16 state chain hs[i-1] -> hs[i] (no oa rmw)
    for (int hop = 1; hop <= KHOPS; ++hop) {
        propagate<<<ceil_div(N_NODES, 4), 256, 0, stream>>>(
            hs + (size_t)(hop - 1) * SSTRIDE, hs + (size_t)hop * SSTRIDE,
            row_ptr, col, N_NODES);
    }

    // oa = sum_i w[i]*hs[i] fused with bn3 stats; then bn3+relu+bf16 once
    wsum_stats<<<256, 256, 0, stream>>>(hs, wts, oa, st3, N_NODES);
    bn3_relu_bf16<<<ceil_div(N_NODES * DIM_P / 8, 256), 256, 0, stream>>>(
        oa, st3, g3, be3, ABF);

    // output: out = ABF @ Wout + bout   (bf16 MFMA, column-persistent waves)
    out_gemm_mfma<<<dim3(512, 4), 256, 0, stream>>>(ABF, WT, bout, out);
}

// Round 12
// 759.564 us; speedup vs baseline: 1.1488x; 1.0005x over previous
//
#include <hip/hip_runtime.h>
#include <cstdint>
#include <cstddef>

#define N_NODES 50000
#define N_EDGES 800000
#define DIM_H   128
#define DIM_P   64     // propagation width after commuting W3
#define DIM_OUT 1000
#define OUT_PAD 1024   // padded col count for MFMA tiles
#define KHOPS   10
#define BN_EPS  1e-5f

static inline int ceil_div(int a, int b) { return (a + b - 1) / b; }

typedef short  bf16x8  __attribute__((ext_vector_type(8)));
typedef float  floatx4 __attribute__((ext_vector_type(4)));

__device__ __forceinline__ unsigned short f2bf_rne(float v) {
    unsigned int u = __float_as_uint(v);
    return (unsigned short)((u + 0x7fffu + ((u >> 16) & 1u)) >> 16);
}
__device__ __forceinline__ float bf2f(unsigned short u) {
    return __uint_as_float((unsigned int)u << 16);
}

// ------- init: softmax(att) + Wout transpose/bf16 + zero st/deg, one kernel ---
__global__ void init_all(const float* __restrict__ att, float* __restrict__ w,
                         const float* __restrict__ Wout, unsigned short* __restrict__ WT,
                         double* __restrict__ st, int* __restrict__ deg) {
    const int gid = blockIdx.x * blockDim.x + threadIdx.x;
    const int stride = gridDim.x * blockDim.x;
    if (gid == 0) {
        float mx = att[0];
        for (int i = 1; i < KHOPS + 1; ++i) mx = fmaxf(mx, att[i]);
        float e[KHOPS + 1];
        float s = 0.f;
        for (int i = 0; i < KHOPS + 1; ++i) { e[i] = expf(att[i] - mx); s += e[i]; }
        for (int i = 0; i < KHOPS + 1; ++i) w[i] = e[i] / s;
    }
    for (int i = gid; i < 640; i += stride) st[i] = 0.0;
    for (int i = gid; i < N_NODES; i += stride) deg[i] = 0;
    for (int i = gid; i < OUT_PAD * DIM_P; i += stride) {
        int c = i >> 6, k = i & 63;
        WT[i] = (c < DIM_OUT) ? f2bf_rne(Wout[(size_t)k * DIM_OUT + c]) : (unsigned short)0;
    }
}

// ---------------- CSR build ----------------
__global__ void count_deg(const int* __restrict__ dst, int* __restrict__ deg, int ne) {
    int i = blockIdx.x * blockDim.x + threadIdx.x;
    if (i < ne) atomicAdd(&deg[dst[i]], 1);
}

// local inclusive scan per 1024-block (shuffle-based, 3 barriers)
__global__ __launch_bounds__(1024) void scan_local(const int* __restrict__ deg,
                                                   int* __restrict__ row_ptr,
                                                   int* __restrict__ bsums, int n) {
    __shared__ int wsum[16];
    const int i = blockIdx.x * 1024 + threadIdx.x;
    const int lane = threadIdx.x & 63, w = threadIdx.x >> 6;
    int v = (i < n) ? deg[i] : 0;
    int s = v;
#pragma unroll
    for (int d = 1; d < 64; d <<= 1) {
        int t = __shfl_up(s, d, 64);
        if (lane >= d) s += t;
    }
    if (lane == 63) wsum[w] = s;
    __syncthreads();
    if (w == 0) {
        int x = (lane < 16) ? wsum[lane] : 0;
#pragma unroll
        for (int d = 1; d < 16; d <<= 1) {
            int t = __shfl_up(x, d, 64);
            if (lane >= d) x += t;
        }
        if (lane < 16) wsum[lane] = x;
    }
    __syncthreads();
    int incl = s + ((w > 0) ? wsum[w - 1] : 0);
    if (i < n) row_ptr[i + 1] = incl;
    if (threadIdx.x == 1023) bsums[blockIdx.x] = incl;
}

// add block offsets (block-sum exclusive scan redone per block in wave 0);
// also derive fill-cursor (exclusive start) in-place in deg
__global__ void scan_finish(int* __restrict__ row_ptr, int* __restrict__ deg,
                            const int* __restrict__ bsums, int n, int nb) {
    __shared__ int boff[64];
    if (threadIdx.x < 64) {
        int lane = threadIdx.x;
        int v = (lane < nb) ? bsums[lane] : 0;
        int s = v;
#pragma unroll
        for (int d = 1; d < 64; d <<= 1) {
            int t = __shfl_up(s, d, 64);
            if (lane >= d) s += t;
        }
        boff[lane] = s - v;   // exclusive prefix
    }
    __syncthreads();
    int i = blockIdx.x * blockDim.x + threadIdx.x;
    if (i < n) {
        int incl = row_ptr[i + 1] + boff[i >> 10];
        row_ptr[i + 1] = incl;
        deg[i] = incl - deg[i];   // cursor = exclusive prefix
    }
    if (i == 0) row_ptr[0] = 0;
}

__global__ void fill_csr(const int* __restrict__ src, const int* __restrict__ dst,
                         int* __restrict__ cursor, int* __restrict__ col, int ne) {
    int i = blockIdx.x * blockDim.x + threadIdx.x;
    if (i < ne) {
        int d = dst[i];
        int pos = atomicAdd(&cursor[d], 1);
        col[pos] = src[i];
    }
}

// ---------------- fused GEMM: C[n,M] = act(A) @ W (fp32) -------------------
// act(A) row = relu(A*sc+sh) [if stA] + relu(A2*sc2+sh2) [if A2]; BN scale/shift
// computed IN-KERNEL from double stats. OBF: C stored bf16 (hop state).
// NO fused stats (R9 lesson: atomics on the GEMM critical path cost +73us).
template<int KD, int CPB, bool OBF>
__global__ __launch_bounds__(256) void gemm_fused(
    const float* __restrict__ A,  const double* __restrict__ stA,
    const float* __restrict__ gA, const float* __restrict__ beA,
    const float* __restrict__ A2, const double* __restrict__ stA2,
    const float* __restrict__ gA2, const float* __restrict__ beA2,
    const float* __restrict__ W,
    float* __restrict__ C, int n, int M) {
    constexpr int CG  = CPB / 4;     // col groups per block
    constexpr int RG  = 256 / CG;    // row groups
    constexpr int RPT = 64 / RG;     // rows per thread
    __shared__ float As[64][KD + 4];
    __shared__ float scA_l[2][KD];
    __shared__ float scA2_l[2][KD];

    const int tid  = threadIdx.x;
    const int cg   = tid % CG;
    const int rg   = tid / CG;
    const int row0 = blockIdx.x * 64;
    const int col0 = blockIdx.y * CPB + cg * 4;

    // inline bn_finalize (identical math to the old separate kernel)
    if (stA && tid < KD) {
        double m = stA[tid] / n;
        double v = stA[KD + tid] / n - m * m;
        float scale = gA[tid] * rsqrtf((float)v + BN_EPS);
        scA_l[0][tid] = scale;
        scA_l[1][tid] = beA[tid] - (float)m * scale;
    }
    if (A2 && tid < KD) {
        double m = stA2[tid] / n;
        double v = stA2[KD + tid] / n - m * m;
        float scale = gA2[tid] * rsqrtf((float)v + BN_EPS);
        scA2_l[0][tid] = scale;
        scA2_l[1][tid] = beA2[tid] - (float)m * scale;
    }
    if (stA || A2) __syncthreads();

    constexpr int VECS = 64 * KD / 4;
    for (int i = tid; i < VECS; i += 256) {
        int r  = i / (KD / 4);
        int k4 = (i % (KD / 4)) * 4;
        float4 v = make_float4(0.f, 0.f, 0.f, 0.f);
        int row = row0 + r;
        if (row < n) {
            v = *reinterpret_cast<const float4*>(A + (size_t)row * KD + k4);
            if (stA) {
                float4 sc = *reinterpret_cast<const float4*>(&scA_l[0][k4]);
                float4 sh = *reinterpret_cast<const float4*>(&scA_l[1][k4]);
                v.x = fmaxf(v.x * sc.x + sh.x, 0.f);
                v.y = fmaxf(v.y * sc.y + sh.y, 0.f);
                v.z = fmaxf(v.z * sc.z + sh.z, 0.f);
                v.w = fmaxf(v.w * sc.w + sh.w, 0.f);
            }
            if (A2) {
                float4 u  = *reinterpret_cast<const float4*>(A2 + (size_t)row * KD + k4);
                float4 sc = *reinterpret_cast<const float4*>(&scA2_l[0][k4]);
                float4 sh = *reinterpret_cast<const float4*>(&scA2_l[1][k4]);
                v.x += fmaxf(u.x * sc.x + sh.x, 0.f);
                v.y += fmaxf(u.y * sc.y + sh.y, 0.f);
                v.z += fmaxf(u.z * sc.z + sh.z, 0.f);
                v.w += fmaxf(u.w * sc.w + sh.w, 0.f);
            }
        }
        *reinterpret_cast<float4*>(&As[r][k4]) = v;
    }
    __syncthreads();

    if (col0 >= M) return;

    float acc[RPT][4];
#pragma unroll
    for (int r = 0; r < RPT; ++r)
#pragma unroll
        for (int c = 0; c < 4; ++c) acc[r][c] = 0.f;

    for (int k4 = 0; k4 < KD; k4 += 4) {
        float4 w0 = *reinterpret_cast<const float4*>(W + (size_t)(k4 + 0) * M + col0);
        float4 w1 = *reinterpret_cast<const float4*>(W + (size_t)(k4 + 1) * M + col0);
        float4 w2 = *reinterpret_cast<const float4*>(W + (size_t)(k4 + 2) * M + col0);
        float4 w3 = *reinterpret_cast<const float4*>(W + (size_t)(k4 + 3) * M + col0);
#pragma unroll
        for (int r = 0; r < RPT; ++r) {
            float4 a = *reinterpret_cast<const float4*>(&As[rg * RPT + r][k4]);
            acc[r][0] += a.x * w0.x + a.y * w1.x + a.z * w2.x + a.w * w3.x;
            acc[r][1] += a.x * w0.y + a.y * w1.y + a.z * w2.y + a.w * w3.y;
            acc[r][2] += a.x * w0.z + a.y * w1.z + a.z * w2.z + a.w * w3.z;
            acc[r][3] += a.x * w0.w + a.y * w1.w + a.z * w2.w + a.w * w3.w;
        }
    }

#pragma unroll
    for (int r = 0; r < RPT; ++r) {
        int row = row0 + rg * RPT + r;
        if (row < n) {
            float4 o = make_float4(acc[r][0], acc[r][1], acc[r][2], acc[r][3]);
            if (OBF) {
                unsigned short* cb = reinterpret_cast<unsigned short*>(C);
                ushort4 p;
                p.x = f2bf_rne(o.x); p.y = f2bf_rne(o.y);
                p.z = f2bf_rne(o.z); p.w = f2bf_rne(o.w);
                *reinterpret_cast<ushort4*>(cb + (size_t)row * M + col0) = p;
            } else {
                *reinterpret_cast<float4*>(C + (size_t)row * M + col0) = o;
            }
        }
    }
}

// ---------------- BN column stats (sum, sumsq) in double ----------------
template<int M>
__global__ __launch_bounds__(256) void colstats(const float* __restrict__ Z,
                                                double* __restrict__ st, int n) {
    constexpr int RG = 256 / M;
    const int tid = threadIdx.x;
    const int c = tid % M, rg = tid / M;
    double s = 0.0, ss = 0.0;
    for (int row = blockIdx.x * RG + rg; row < n; row += gridDim.x * RG) {
        float v = Z[(size_t)row * M + c];
        s += v;
        ss += (double)v * (double)v;
    }
    __shared__ double sh[2][256];
    sh[0][tid] = s;
    sh[1][tid] = ss;
    __syncthreads();
    if (rg == 0) {
#pragma unroll
        for (int g = 1; g < RG; ++g) { s += sh[0][c + g * M]; ss += sh[1][c + g * M]; }
        atomicAdd(&st[c], s);
        atomicAdd(&st[M + c], ss);
    }
}

// ---------------- one propagation hop (CSR gather-sum, bf16 state) -----------
// Pure gather: no oacc rmw (weighted sum deferred to wsum_stats). Hop state
// rows are 64 bf16 = 128B. 8 lanes x 16B cover one row; 8 lane-groups process
// 8 neighbors per wave vmem instruction; x2 unrolled = 16 in flight.
__global__ __launch_bounds__(256) void propagate(
    const unsigned short* __restrict__ cur, unsigned short* __restrict__ nxt,
    const int* __restrict__ row_ptr, const int* __restrict__ col, int n) {
    const int node = blockIdx.x * 4 + (threadIdx.x >> 6);
    const int lane = threadIdx.x & 63;
    const int g = lane >> 3;      // neighbor slot 0..7
    const int l = lane & 7;       // feature oct: features l*8 .. l*8+7
    if (node >= n) return;
    const int beg = row_ptr[node], end = row_ptr[node + 1];
    float acc[8];
#pragma unroll
    for (int j = 0; j < 8; ++j) acc[j] = 0.f;

    int e = beg;
    for (; e + 16 <= end; e += 16) {
        int s0 = col[e + g];
        int s1 = col[e + g + 8];
        bf16x8 v0 = *reinterpret_cast<const bf16x8*>(cur + (size_t)s0 * DIM_P + l * 8);
        bf16x8 v1 = *reinterpret_cast<const bf16x8*>(cur + (size_t)s1 * DIM_P + l * 8);
#pragma unroll
        for (int j = 0; j < 8; ++j)
            acc[j] += bf2f((unsigned short)v0[j]) + bf2f((unsigned short)v1[j]);
    }
    if (e + 8 <= end) {
        int s = col[e + g];
        bf16x8 v = *reinterpret_cast<const bf16x8*>(cur + (size_t)s * DIM_P + l * 8);
#pragma unroll
        for (int j = 0; j < 8; ++j) acc[j] += bf2f((unsigned short)v[j]);
        e += 8;
    }
    if (e + g < end) {
        int s = col[e + g];
        bf16x8 v = *reinterpret_cast<const bf16x8*>(cur + (size_t)s * DIM_P + l * 8);
#pragma unroll
        for (int j = 0; j < 8; ++j) acc[j] += bf2f((unsigned short)v[j]);
    }

    // reduce across the 8 lane-groups (offsets 8,16,32 keep l fixed)
#pragma unroll
    for (int off = 8; off < 64; off <<= 1) {
#pragma unroll
        for (int j = 0; j < 8; ++j) acc[j] += __shfl_xor(acc[j], off, 64);
    }

    if (g == 0) {
        bf16x8 ov;
#pragma unroll
        for (int j = 0; j < 8; ++j) ov[j] = (short)f2bf_rne(acc[j]);
        *reinterpret_cast<bf16x8*>(nxt + (size_t)node * DIM_P + l * 8) = ov;
    }
}

// ------- weighted hop sum + bn3 stats: oa = sum_i w[i]*hs[i]; st3 += stats ----
__global__ __launch_bounds__(256) void wsum_stats(
    const unsigned short* __restrict__ hs, const float* __restrict__ wts,
    float* __restrict__ oa, double* __restrict__ st, int n) {
    const int tid = threadIdx.x;
    const int c = tid & 63, rg = tid >> 6;   // 4 row groups
    float w[KHOPS + 1];
#pragma unroll
    for (int i = 0; i < KHOPS + 1; ++i) w[i] = wts[i];
    const size_t stride = (size_t)n * DIM_P;
    double s = 0.0, ss = 0.0;
    for (int row = blockIdx.x * 4 + rg; row < n; row += gridDim.x * 4) {
        const size_t idx = (size_t)row * DIM_P + c;
        float val = 0.f;
#pragma unroll
        for (int i = 0; i < KHOPS + 1; ++i)
            val += w[i] * bf2f(hs[idx + (size_t)i * stride]);
        oa[idx] = val;
        s += val;
        ss += (double)val * (double)val;
    }
    __shared__ double sh[2][256];
    sh[0][tid] = s;
    sh[1][tid] = ss;
    __syncthreads();
    if (rg == 0) {
#pragma unroll
        for (int g2 = 1; g2 < 4; ++g2) { s += sh[0][c + g2 * 64]; ss += sh[1][c + g2 * 64]; }
        atomicAdd(&st[c], s);
        atomicAdd(&st[64 + c], ss);
    }
}

// -------- final GEMM via MFMA with inline bn3+relu+bf16 on the B side --------
// out = relu(bn3(oa)) @ Wout + bout. A-operand = Wout columns (register-
// resident across the row loop), B = bn3'd node rows (built per tile from fp32
// oa — same fused pattern as the verified round-0 A-side). D: lane&15 ->
// node row, quad*4+reg -> out col; each lane stores float4 of 4 columns.
__global__ __launch_bounds__(256, 4) void out_gemm_mfma(
    const float* __restrict__ oa, const double* __restrict__ st3,
    const float* __restrict__ g3, const float* __restrict__ be3,
    const unsigned short* __restrict__ WT,
    const float* __restrict__ bout, float* __restrict__ out) {
    __shared__ float sc[DIM_P], sh[DIM_P];
    if (threadIdx.x < DIM_P) {
        int c = threadIdx.x;
        double m = st3[c] / N_NODES;
        double v = st3[DIM_P + c] / N_NODES - m * m;
        float scale = g3[c] * rsqrtf((float)v + BN_EPS);
        sc[c] = scale;
        sh[c] = be3[c] - (float)m * scale;
    }
    __syncthreads();

    const int wave = threadIdx.x >> 6;
    const int lane = threadIdx.x & 63;
    const int m    = lane & 15;       // A: out-col within tile; B/D: out-row
    const int quad = lane >> 4;
    const int kb   = quad * 8;
    const int c0   = blockIdx.y * 256 + wave * 64;

    bf16x8 afrag[4][2];
    float4 bias[4];
#pragma unroll
    for (int t = 0; t < 4; ++t) {
        const unsigned short* wrow = WT + (size_t)(c0 + t * 16 + m) * DIM_P;
        afrag[t][0] = *reinterpret_cast<const bf16x8*>(wrow + kb);
        afrag[t][1] = *reinterpret_cast<const bf16x8*>(wrow + 32 + kb);
        int cc = c0 + t * 16 + quad * 4;
        bias[t] = (cc < DIM_OUT) ? *reinterpret_cast<const float4*>(bout + cc)
                                 : make_float4(0.f, 0.f, 0.f, 0.f);
    }

    const int NT = N_NODES / 16;  // 3125 row tiles
    for (int rt = blockIdx.x; rt < NT; rt += gridDim.x) {
        const int row = rt * 16 + m;
        const float* arow = oa + (size_t)row * DIM_P;
        bf16x8 bfrag[2];
#pragma unroll
        for (int kh = 0; kh < 2; ++kh) {
            const int k0 = kh * 32 + kb;
            float4 a0 = *reinterpret_cast<const float4*>(arow + k0);
            float4 a1 = *reinterpret_cast<const float4*>(arow + k0 + 4);
            float4 s0 = *reinterpret_cast<const float4*>(&sc[k0]);
            float4 s1 = *reinterpret_cast<const float4*>(&sc[k0 + 4]);
            float4 h0 = *reinterpret_cast<const float4*>(&sh[k0]);
            float4 h1 = *reinterpret_cast<const float4*>(&sh[k0 + 4]);
            bfrag[kh][0] = (short)f2bf_rne(fmaxf(a0.x * s0.x + h0.x, 0.f));
            bfrag[kh][1] = (short)f2bf_rne(fmaxf(a0.y * s0.y + h0.y, 0.f));
            bfrag[kh][2] = (short)f2bf_rne(fmaxf(a0.z * s0.z + h0.z, 0.f));
            bfrag[kh][3] = (short)f2bf_rne(fmaxf(a0.w * s0.w + h0.w, 0.f));
            bfrag[kh][4] = (short)f2bf_rne(fmaxf(a1.x * s1.x + h1.x, 0.f));
            bfrag[kh][5] = (short)f2bf_rne(fmaxf(a1.y * s1.y + h1.y, 0.f));
            bfrag[kh][6] = (short)f2bf_rne(fmaxf(a1.z * s1.z + h1.z, 0.f));
            bfrag[kh][7] = (short)f2bf_rne(fmaxf(a1.w * s1.w + h1.w, 0.f));
        }
        float* orow = out + (size_t)row * DIM_OUT;
#pragma unroll
        for (int t = 0; t < 4; ++t) {
            floatx4 acc = {0.f, 0.f, 0.f, 0.f};
            acc = __builtin_amdgcn_mfma_f32_16x16x32_bf16(afrag[t][0], bfrag[0], acc, 0, 0, 0);
            acc = __builtin_amdgcn_mfma_f32_16x16x32_bf16(afrag[t][1], bfrag[1], acc, 0, 0, 0);
            int cc = c0 + t * 16 + quad * 4;
            if (cc < DIM_OUT) {
                float4 o = make_float4(acc[0] + bias[t].x, acc[1] + bias[t].y,
                                       acc[2] + bias[t].z, acc[3] + bias[t].w);
                *reinterpret_cast<float4*>(orow + cc) = o;
            }
        }
    }
}

// ---------------- launch ----------------
extern "C" void kernel_launch(void* const* d_in, const int* in_sizes, int n_in,
                              void* d_out, int out_size, void* d_ws, size_t ws_size,
                              hipStream_t stream) {
    const float* x    = (const float*)d_in[0];
    const int*   ei   = (const int*)  d_in[1];
    const float* W1   = (const float*)d_in[2];
    const float* g1   = (const float*)d_in[4];
    const float* be1  = (const float*)d_in[5];
    const float* W2   = (const float*)d_in[6];
    const float* g2   = (const float*)d_in[8];
    const float* be2  = (const float*)d_in[9];
    const float* att  = (const float*)d_in[10];
    const float* W3   = (const float*)d_in[11];
    const float* g3   = (const float*)d_in[13];
    const float* be3  = (const float*)d_in[14];
    const float* Wout = (const float*)d_in[15];
    const float* bout = (const float*)d_in[16];
    float* out = (float*)d_out;

    char* base = (char*)d_ws;
    size_t off = 0;
    auto alloc = [&](size_t bytes) -> void* {
        void* r = base + off;
        off += (bytes + 255) & ~(size_t)255;
        return r;
    };
    const size_t SSTRIDE = (size_t)N_NODES * DIM_P;   // elements per hop state
    float*  f0      = (float*) alloc((size_t)N_NODES * DIM_H * 4); // z1
    float*  f1      = (float*) alloc((size_t)N_NODES * DIM_H * 4); // z2
    unsigned short* hs = (unsigned short*)alloc((size_t)(KHOPS + 1) * SSTRIDE * 2);
    float*  oa      = (float*) alloc(SSTRIDE * 4);    // fp32 weighted acc
    double* st      = (double*)alloc(640 * 8);
    float*  wts     = (float*) alloc(16 * 4);
    int*    row_ptr = (int*)   alloc((size_t)(N_NODES + 1) * 4);
    int*    deg     = (int*)   alloc((size_t)N_NODES * 4);   // degree -> cursor
    int*    col     = (int*)   alloc((size_t)N_EDGES * 4);
    int*    bsums   = (int*)   alloc(64 * 4);
    unsigned short* WT = (unsigned short*)alloc((size_t)OUT_PAD * DIM_P * 2);

    const int* src = ei;
    const int* dst = ei + N_EDGES;
    double* st1 = st;   double* st2 = st + 256; double* st3 = st + 512;

    // 1 dispatch: softmax + Wout prep + zero stats/deg
    init_all<<<256, 256, 0, stream>>>(att, wts, Wout, WT, st, deg);

    // CSR by destination (4 dispatches; bsums scan folded into scan_finish)
    count_deg<<<ceil_div(N_EDGES, 256), 256, 0, stream>>>(dst, deg, N_EDGES);
    const int NB = ceil_div(N_NODES, 1024);
    scan_local<<<NB, 1024, 0, stream>>>(deg, row_ptr, bsums, N_NODES);
    scan_finish<<<ceil_div(N_NODES, 256), 256, 0, stream>>>(row_ptr, deg, bsums,
                                                            N_NODES, NB);
    fill_csr<<<ceil_div(N_EDGES, 256), 256, 0, stream>>>(src, dst, deg, col, N_EDGES);

    const int RB = ceil_div(N_NODES, 64);

    // layer 1: z1 = x@W1 (b1 cancels in BN); stats via separate colstats
    gemm_fused<128, 128, false><<<dim3(RB, 1), 256, 0, stream>>>(
        x, nullptr, nullptr, nullptr,
        nullptr, nullptr, nullptr, nullptr,
        W1, f0, N_NODES, DIM_H);
    colstats<128><<<256, 256, 0, stream>>>(f0, st1, N_NODES);

    // layer 2: z2 = relu(bn1(z1))@W2, bn1 finalized in-kernel
    gemm_fused<128, 128, false><<<dim3(RB, 1), 256, 0, stream>>>(
        f0, st1, g1, be1,
        nullptr, nullptr, nullptr, nullptr,
        W2, f1, N_NODES, DIM_H);
    colstats<128><<<256, 256, 0, stream>>>(f1, st2, N_NODES);

    // layer 3 input: h2 = relu(bn2(z2)) + relu(bn1(z1)); y = h2@W3 -> hs[0] bf16
    gemm_fused<128, 64, true><<<dim3(RB, 1), 256, 0, stream>>>(
        f1, st2, g2, be2,
        f0, st1, g1, be1,
        W3, (float*)hs, N_NODES, DIM_P);

    // 10 hops over the bf16 state chain hs[i-1] -> hs[i] (no oa rmw)
    for (int hop = 1; hop <= KHOPS; ++hop) {
        propagate<<<ceil_div(N_NODES, 4), 256, 0, stream>>>(
            hs + (size_t)(hop - 1) * SSTRIDE, hs + (size_t)hop * SSTRIDE,
            row_ptr, col, N_NODES);
    }

    // oa = sum_i w[i]*hs[i] fused with bn3 stats
    wsum_stats<<<256, 256, 0, stream>>>(hs, wts, oa, st3, N_NODES);

    // output: out = relu(bn3(oa)) @ Wout + bout (bn3 fused into the MFMA GEMM)
    out_gemm_mfma<<<dim3(512, 4), 256, 0, stream>>>(oa, st3, g3, be3, WT, bout, out);
}

// Round 13
// 724.560 us; speedup vs baseline: 1.2042x; 1.0483x over previous
//
#include <hip/hip_runtime.h>
#include <cstdint>
#include <cstddef>

#define N_NODES 50000
#define N_EDGES 800000
#define DIM_H   128
#define DIM_P   64     // propagation width after commuting W3
#define DIM_OUT 1000
#define OUT_PAD 1024   // padded col count for MFMA tiles
#define KHOPS   10
#define BN_EPS  1e-5f

static inline int ceil_div(int a, int b) { return (a + b - 1) / b; }

typedef short  bf16x8  __attribute__((ext_vector_type(8)));
typedef float  floatx4 __attribute__((ext_vector_type(4)));

__device__ __forceinline__ unsigned short f2bf_rne(float v) {
    unsigned int u = __float_as_uint(v);
    return (unsigned short)((u + 0x7fffu + ((u >> 16) & 1u)) >> 16);
}
__device__ __forceinline__ float bf2f(unsigned short u) {
    return __uint_as_float((unsigned int)u << 16);
}

// -- init: softmax(att) + Wout prep + hi/lo split weight transposes + zeroing --
// Split: Wh = bf16(W), Wl = bf16(W - Wh); A@W ~ Ah@Wh + Al@Wh + Ah@Wl with
// residual <= 2^-18 relative (fp32-indistinguishable at bf16 output grain).
__global__ void init_all(const float* __restrict__ att, float* __restrict__ w,
                         const float* __restrict__ Wout, unsigned short* __restrict__ WT,
                         const float* __restrict__ W1, unsigned short* __restrict__ WT1h,
                         unsigned short* __restrict__ WT1l,
                         const float* __restrict__ W2, unsigned short* __restrict__ WT2h,
                         unsigned short* __restrict__ WT2l,
                         const float* __restrict__ W3, unsigned short* __restrict__ WT3h,
                         unsigned short* __restrict__ WT3l,
                         double* __restrict__ st, int* __restrict__ deg) {
    const int gid = blockIdx.x * blockDim.x + threadIdx.x;
    const int stride = gridDim.x * blockDim.x;
    if (gid == 0) {
        float mx = att[0];
        for (int i = 1; i < KHOPS + 1; ++i) mx = fmaxf(mx, att[i]);
        float e[KHOPS + 1];
        float s = 0.f;
        for (int i = 0; i < KHOPS + 1; ++i) { e[i] = expf(att[i] - mx); s += e[i]; }
        for (int i = 0; i < KHOPS + 1; ++i) w[i] = e[i] / s;
    }
    for (int i = gid; i < 640; i += stride) st[i] = 0.0;
    for (int i = gid; i < N_NODES; i += stride) deg[i] = 0;
    for (int i = gid; i < OUT_PAD * DIM_P; i += stride) {
        int c = i >> 6, k = i & 63;
        WT[i] = (c < DIM_OUT) ? f2bf_rne(Wout[(size_t)k * DIM_OUT + c]) : (unsigned short)0;
    }
    // WT1/WT2: [128][128], WTx[m][k] = W[k][m] split hi/lo
    for (int i = gid; i < DIM_H * DIM_H; i += stride) {
        int m = i >> 7, k = i & 127;
        float w1v = W1[(size_t)k * DIM_H + m];
        unsigned short h1 = f2bf_rne(w1v);
        WT1h[i] = h1;
        WT1l[i] = f2bf_rne(w1v - bf2f(h1));
        float w2v = W2[(size_t)k * DIM_H + m];
        unsigned short h2 = f2bf_rne(w2v);
        WT2h[i] = h2;
        WT2l[i] = f2bf_rne(w2v - bf2f(h2));
    }
    // WT3: [64][128] split hi/lo
    for (int i = gid; i < DIM_P * DIM_H; i += stride) {
        int m = i >> 7, k = i & 127;
        float w3v = W3[(size_t)k * DIM_P + m];
        unsigned short h3 = f2bf_rne(w3v);
        WT3h[i] = h3;
        WT3l[i] = f2bf_rne(w3v - bf2f(h3));
    }
}

// ---------------- CSR build ----------------
__global__ void count_deg(const int* __restrict__ dst, int* __restrict__ deg, int ne) {
    int i = blockIdx.x * blockDim.x + threadIdx.x;
    if (i < ne) atomicAdd(&deg[dst[i]], 1);
}

// local inclusive scan per 1024-block (shuffle-based, 3 barriers)
__global__ __launch_bounds__(1024) void scan_local(const int* __restrict__ deg,
                                                   int* __restrict__ row_ptr,
                                                   int* __restrict__ bsums, int n) {
    __shared__ int wsum[16];
    const int i = blockIdx.x * 1024 + threadIdx.x;
    const int lane = threadIdx.x & 63, w = threadIdx.x >> 6;
    int v = (i < n) ? deg[i] : 0;
    int s = v;
#pragma unroll
    for (int d = 1; d < 64; d <<= 1) {
        int t = __shfl_up(s, d, 64);
        if (lane >= d) s += t;
    }
    if (lane == 63) wsum[w] = s;
    __syncthreads();
    if (w == 0) {
        int x = (lane < 16) ? wsum[lane] : 0;
#pragma unroll
        for (int d = 1; d < 16; d <<= 1) {
            int t = __shfl_up(x, d, 64);
            if (lane >= d) x += t;
        }
        if (lane < 16) wsum[lane] = x;
    }
    __syncthreads();
    int incl = s + ((w > 0) ? wsum[w - 1] : 0);
    if (i < n) row_ptr[i + 1] = incl;
    if (threadIdx.x == 1023) bsums[blockIdx.x] = incl;
}

// add block offsets (block-sum exclusive scan redone per block in wave 0);
// also derive fill-cursor (exclusive start) in-place in deg
__global__ void scan_finish(int* __restrict__ row_ptr, int* __restrict__ deg,
                            const int* __restrict__ bsums, int n, int nb) {
    __shared__ int boff[64];
    if (threadIdx.x < 64) {
        int lane = threadIdx.x;
        int v = (lane < nb) ? bsums[lane] : 0;
        int s = v;
#pragma unroll
        for (int d = 1; d < 64; d <<= 1) {
            int t = __shfl_up(s, d, 64);
            if (lane >= d) s += t;
        }
        boff[lane] = s - v;   // exclusive prefix
    }
    __syncthreads();
    int i = blockIdx.x * blockDim.x + threadIdx.x;
    if (i < n) {
        int incl = row_ptr[i + 1] + boff[i >> 10];
        row_ptr[i + 1] = incl;
        deg[i] = incl - deg[i];   // cursor = exclusive prefix
    }
    if (i == 0) row_ptr[0] = 0;
}

__global__ void fill_csr(const int* __restrict__ src, const int* __restrict__ dst,
                         int* __restrict__ cursor, int* __restrict__ col, int ne) {
    int i = blockIdx.x * blockDim.x + threadIdx.x;
    if (i < ne) {
        int d = dst[i];
        int pos = atomicAdd(&cursor[d], 1);
        col[pos] = src[i];
    }
}

// ------- split-bf16 MFMA GEMM: C[n,M] = act(A) @ W, fp32-accurate -----------
// act(A) = relu(A*sc+sh) [if stA] (+ relu(A2*sc2+sh2) if DUAL), computed fp32,
// then split A = Ah + Al (each bf16). acc = Wh*Ah + Wl*Ah + Wh*Al (fp32 MFMA
// accumulate; dropped Wl*Al <= 2^-18 rel). Fragment layout mirrors the
// harness-verified out_gemm_mfma: A-op = weight rows (WTx[m][k]), B-op = act
// rows; D: lane&15 -> act row, (lane>>4)*4+reg -> weight col.
// OBF: C stored bf16 (hop state), else fp32.
template<int M, bool DUAL, bool OBF>
__global__ __launch_bounds__(256) void gemm_mfma_split(
    const float* __restrict__ A,  const double* __restrict__ stA,
    const float* __restrict__ gA, const float* __restrict__ beA,
    const float* __restrict__ A2, const double* __restrict__ stA2,
    const float* __restrict__ gA2, const float* __restrict__ beA2,
    const unsigned short* __restrict__ WTh, const unsigned short* __restrict__ WTl,
    float* __restrict__ C, int n) {
    constexpr int K  = 128;
    constexpr int CT = M / 64;          // col-tiles per wave (M=128 -> 2, 64 -> 1)
    __shared__ __align__(16) unsigned short Ah[64][K + 8];
    __shared__ __align__(16) unsigned short Al[64][K + 8];
    __shared__ __align__(16) float scl[2][K];
    __shared__ __align__(16) float scl2[2][K];

    const int tid  = threadIdx.x;
    const int wave = tid >> 6;
    const int lane = tid & 63;
    const int m15  = lane & 15;
    const int quad = lane >> 4;
    const int row0 = blockIdx.x * 64;

    // inline bn_finalize (identical math to R12)
    if (stA && tid < K) {
        double mm = stA[tid] / n;
        double vv = stA[K + tid] / n - mm * mm;
        float scale = gA[tid] * rsqrtf((float)vv + BN_EPS);
        scl[0][tid] = scale;
        scl[1][tid] = beA[tid] - (float)mm * scale;
    }
    if (DUAL && tid < K) {
        double mm = stA2[tid] / n;
        double vv = stA2[K + tid] / n - mm * mm;
        float scale = gA2[tid] * rsqrtf((float)vv + BN_EPS);
        scl2[0][tid] = scale;
        scl2[1][tid] = beA2[tid] - (float)mm * scale;
    }
    __syncthreads();

    // stage act(A) as hi/lo bf16 tiles: 64 rows x 128 cols
    for (int i = tid; i < 64 * 32; i += 256) {
        int r  = i >> 5;
        int k4 = (i & 31) * 4;
        float4 v = make_float4(0.f, 0.f, 0.f, 0.f);
        int row = row0 + r;
        if (row < n) {
            v = *reinterpret_cast<const float4*>(A + (size_t)row * K + k4);
            if (stA) {
                float4 sc = *reinterpret_cast<const float4*>(&scl[0][k4]);
                float4 sh = *reinterpret_cast<const float4*>(&scl[1][k4]);
                v.x = fmaxf(v.x * sc.x + sh.x, 0.f);
                v.y = fmaxf(v.y * sc.y + sh.y, 0.f);
                v.z = fmaxf(v.z * sc.z + sh.z, 0.f);
                v.w = fmaxf(v.w * sc.w + sh.w, 0.f);
            }
            if (DUAL) {
                float4 u  = *reinterpret_cast<const float4*>(A2 + (size_t)row * K + k4);
                float4 sc = *reinterpret_cast<const float4*>(&scl2[0][k4]);
                float4 sh = *reinterpret_cast<const float4*>(&scl2[1][k4]);
                v.x += fmaxf(u.x * sc.x + sh.x, 0.f);
                v.y += fmaxf(u.y * sc.y + sh.y, 0.f);
                v.z += fmaxf(u.z * sc.z + sh.z, 0.f);
                v.w += fmaxf(u.w * sc.w + sh.w, 0.f);
            }
        }
        ushort4 ph, pl;
        ph.x = f2bf_rne(v.x); pl.x = f2bf_rne(v.x - bf2f(ph.x));
        ph.y = f2bf_rne(v.y); pl.y = f2bf_rne(v.y - bf2f(ph.y));
        ph.z = f2bf_rne(v.z); pl.z = f2bf_rne(v.z - bf2f(ph.z));
        ph.w = f2bf_rne(v.w); pl.w = f2bf_rne(v.w - bf2f(ph.w));
        *reinterpret_cast<ushort4*>(&Ah[r][k4]) = ph;
        *reinterpret_cast<ushort4*>(&Al[r][k4]) = pl;
    }
    __syncthreads();

    // weight fragments hi/lo (register-resident): col = wave*CT*16 + t*16 + m15
    bf16x8 afh[CT][4], afl[CT][4];
#pragma unroll
    for (int t = 0; t < CT; ++t) {
        const size_t wroff = (size_t)(wave * CT * 16 + t * 16 + m15) * K + quad * 8;
#pragma unroll
        for (int ch = 0; ch < 4; ++ch) {
            afh[t][ch] = *reinterpret_cast<const bf16x8*>(WTh + wroff + ch * 32);
            afl[t][ch] = *reinterpret_cast<const bf16x8*>(WTl + wroff + ch * 32);
        }
    }

    floatx4 acc[CT][4];
#pragma unroll
    for (int t = 0; t < CT; ++t)
#pragma unroll
        for (int rt = 0; rt < 4; ++rt) acc[t][rt] = (floatx4){0.f, 0.f, 0.f, 0.f};

#pragma unroll
    for (int rt = 0; rt < 4; ++rt) {
        bf16x8 bfh[4], bfl[4];
#pragma unroll
        for (int ch = 0; ch < 4; ++ch) {
            bfh[ch] = *reinterpret_cast<const bf16x8*>(&Ah[rt * 16 + m15][ch * 32 + quad * 8]);
            bfl[ch] = *reinterpret_cast<const bf16x8*>(&Al[rt * 16 + m15][ch * 32 + quad * 8]);
        }
#pragma unroll
        for (int t = 0; t < CT; ++t)
#pragma unroll
            for (int ch = 0; ch < 4; ++ch) {
                acc[t][rt] = __builtin_amdgcn_mfma_f32_16x16x32_bf16(
                    afh[t][ch], bfh[ch], acc[t][rt], 0, 0, 0);   // Wh*Ah
                acc[t][rt] = __builtin_amdgcn_mfma_f32_16x16x32_bf16(
                    afl[t][ch], bfh[ch], acc[t][rt], 0, 0, 0);   // Wl*Ah
                acc[t][rt] = __builtin_amdgcn_mfma_f32_16x16x32_bf16(
                    afh[t][ch], bfl[ch], acc[t][rt], 0, 0, 0);   // Wh*Al
            }
    }

#pragma unroll
    for (int t = 0; t < CT; ++t) {
        const int c = wave * CT * 16 + t * 16 + quad * 4;
#pragma unroll
        for (int rt = 0; rt < 4; ++rt) {
            int row = row0 + rt * 16 + m15;
            if (row < n) {
                if (OBF) {
                    unsigned short* cb = reinterpret_cast<unsigned short*>(C);
                    ushort4 p;
                    p.x = f2bf_rne(acc[t][rt][0]);
                    p.y = f2bf_rne(acc[t][rt][1]);
                    p.z = f2bf_rne(acc[t][rt][2]);
                    p.w = f2bf_rne(acc[t][rt][3]);
                    *reinterpret_cast<ushort4*>(cb + (size_t)row * M + c) = p;
                } else {
                    float4 o = make_float4(acc[t][rt][0], acc[t][rt][1],
                                           acc[t][rt][2], acc[t][rt][3]);
                    *reinterpret_cast<float4*>(C + (size_t)row * M + c) = o;
                }
            }
        }
    }
}

// ---------------- BN column stats (sum, sumsq) in double ----------------
template<int M>
__global__ __launch_bounds__(256) void colstats(const float* __restrict__ Z,
                                                double* __restrict__ st, int n) {
    constexpr int RG = 256 / M;
    const int tid = threadIdx.x;
    const int c = tid % M, rg = tid / M;
    double s = 0.0, ss = 0.0;
    for (int row = blockIdx.x * RG + rg; row < n; row += gridDim.x * RG) {
        float v = Z[(size_t)row * M + c];
        s += v;
        ss += (double)v * (double)v;
    }
    __shared__ double sh[2][256];
    sh[0][tid] = s;
    sh[1][tid] = ss;
    __syncthreads();
    if (rg == 0) {
#pragma unroll
        for (int g = 1; g < RG; ++g) { s += sh[0][c + g * M]; ss += sh[1][c + g * M]; }
        atomicAdd(&st[c], s);
        atomicAdd(&st[M + c], ss);
    }
}

// ---------------- one propagation hop (CSR gather-sum, bf16 state) -----------
__global__ __launch_bounds__(256) void propagate(
    const unsigned short* __restrict__ cur, unsigned short* __restrict__ nxt,
    const int* __restrict__ row_ptr, const int* __restrict__ col, int n) {
    const int node = blockIdx.x * 4 + (threadIdx.x >> 6);
    const int lane = threadIdx.x & 63;
    const int g = lane >> 3;      // neighbor slot 0..7
    const int l = lane & 7;       // feature oct: features l*8 .. l*8+7
    if (node >= n) return;
    const int beg = row_ptr[node], end = row_ptr[node + 1];
    float acc[8];
#pragma unroll
    for (int j = 0; j < 8; ++j) acc[j] = 0.f;

    int e = beg;
    for (; e + 16 <= end; e += 16) {
        int s0 = col[e + g];
        int s1 = col[e + g + 8];
        bf16x8 v0 = *reinterpret_cast<const bf16x8*>(cur + (size_t)s0 * DIM_P + l * 8);
        bf16x8 v1 = *reinterpret_cast<const bf16x8*>(cur + (size_t)s1 * DIM_P + l * 8);
#pragma unroll
        for (int j = 0; j < 8; ++j)
            acc[j] += bf2f((unsigned short)v0[j]) + bf2f((unsigned short)v1[j]);
    }
    if (e + 8 <= end) {
        int s = col[e + g];
        bf16x8 v = *reinterpret_cast<const bf16x8*>(cur + (size_t)s * DIM_P + l * 8);
#pragma unroll
        for (int j = 0; j < 8; ++j) acc[j] += bf2f((unsigned short)v[j]);
        e += 8;
    }
    if (e + g < end) {
        int s = col[e + g];
        bf16x8 v = *reinterpret_cast<const bf16x8*>(cur + (size_t)s * DIM_P + l * 8);
#pragma unroll
        for (int j = 0; j < 8; ++j) acc[j] += bf2f((unsigned short)v[j]);
    }

    // reduce across the 8 lane-groups (offsets 8,16,32 keep l fixed)
#pragma unroll
    for (int off = 8; off < 64; off <<= 1) {
#pragma unroll
        for (int j = 0; j < 8; ++j) acc[j] += __shfl_xor(acc[j], off, 64);
    }

    if (g == 0) {
        bf16x8 ov;
#pragma unroll
        for (int j = 0; j < 8; ++j) ov[j] = (short)f2bf_rne(acc[j]);
        *reinterpret_cast<bf16x8*>(nxt + (size_t)node * DIM_P + l * 8) = ov;
    }
}

// ------- weighted hop sum + bn3 stats: oa = sum_i w[i]*hs[i]; st3 += stats ----
__global__ __launch_bounds__(256) void wsum_stats(
    const unsigned short* __restrict__ hs, const float* __restrict__ wts,
    float* __restrict__ oa, double* __restrict__ st, int n) {
    const int tid = threadIdx.x;
    const int c = tid & 63, rg = tid >> 6;   // 4 row groups
    float w[KHOPS + 1];
#pragma unroll
    for (int i = 0; i < KHOPS + 1; ++i) w[i] = wts[i];
    const size_t stride = (size_t)n * DIM_P;
    double s = 0.0, ss = 0.0;
    for (int row = blockIdx.x * 4 + rg; row < n; row += gridDim.x * 4) {
        const size_t idx = (size_t)row * DIM_P + c;
        float val = 0.f;
#pragma unroll
        for (int i = 0; i < KHOPS + 1; ++i)
            val += w[i] * bf2f(hs[idx + (size_t)i * stride]);
        oa[idx] = val;
        s += val;
        ss += (double)val * (double)val;
    }
    __shared__ double sh[2][256];
    sh[0][tid] = s;
    sh[1][tid] = ss;
    __syncthreads();
    if (rg == 0) {
#pragma unroll
        for (int g2 = 1; g2 < 4; ++g2) { s += sh[0][c + g2 * 64]; ss += sh[1][c + g2 * 64]; }
        atomicAdd(&st[c], s);
        atomicAdd(&st[64 + c], ss);
    }
}

// -------- final GEMM via MFMA with inline bn3+relu+bf16 on the B side --------
__global__ __launch_bounds__(256, 4) void out_gemm_mfma(
    const float* __restrict__ oa, const double* __restrict__ st3,
    const float* __restrict__ g3, const float* __restrict__ be3,
    const unsigned short* __restrict__ WT,
    const float* __restrict__ bout, float* __restrict__ out) {
    __shared__ float sc[DIM_P], sh[DIM_P];
    if (threadIdx.x < DIM_P) {
        int c = threadIdx.x;
        double m = st3[c] / N_NODES;
        double v = st3[DIM_P + c] / N_NODES - m * m;
        float scale = g3[c] * rsqrtf((float)v + BN_EPS);
        sc[c] = scale;
        sh[c] = be3[c] - (float)m * scale;
    }
    __syncthreads();

    const int wave = threadIdx.x >> 6;
    const int lane = threadIdx.x & 63;
    const int m    = lane & 15;       // A: out-col within tile; B/D: out-row
    const int quad = lane >> 4;
    const int kb   = quad * 8;
    const int c0   = blockIdx.y * 256 + wave * 64;

    bf16x8 afrag[4][2];
    float4 bias[4];
#pragma unroll
    for (int t = 0; t < 4; ++t) {
        const unsigned short* wrow = WT + (size_t)(c0 + t * 16 + m) * DIM_P;
        afrag[t][0] = *reinterpret_cast<const bf16x8*>(wrow + kb);
        afrag[t][1] = *reinterpret_cast<const bf16x8*>(wrow + 32 + kb);
        int cc = c0 + t * 16 + quad * 4;
        bias[t] = (cc < DIM_OUT) ? *reinterpret_cast<const float4*>(bout + cc)
                                 : make_float4(0.f, 0.f, 0.f, 0.f);
    }

    const int NT = N_NODES / 16;  // 3125 row tiles
    for (int rt = blockIdx.x; rt < NT; rt += gridDim.x) {
        const int row = rt * 16 + m;
        const float* arow = oa + (size_t)row * DIM_P;
        bf16x8 bfrag[2];
#pragma unroll
        for (int kh = 0; kh < 2; ++kh) {
            const int k0 = kh * 32 + kb;
            float4 a0 = *reinterpret_cast<const float4*>(arow + k0);
            float4 a1 = *reinterpret_cast<const float4*>(arow + k0 + 4);
            float4 s0 = *reinterpret_cast<const float4*>(&sc[k0]);
            float4 s1 = *reinterpret_cast<const float4*>(&sc[k0 + 4]);
            float4 h0 = *reinterpret_cast<const float4*>(&sh[k0]);
            float4 h1 = *reinterpret_cast<const float4*>(&sh[k0 + 4]);
            bfrag[kh][0] = (short)f2bf_rne(fmaxf(a0.x * s0.x + h0.x, 0.f));
            bfrag[kh][1] = (short)f2bf_rne(fmaxf(a0.y * s0.y + h0.y, 0.f));
            bfrag[kh][2] = (short)f2bf_rne(fmaxf(a0.z * s0.z + h0.z, 0.f));
            bfrag[kh][3] = (short)f2bf_rne(fmaxf(a0.w * s0.w + h0.w, 0.f));
            bfrag[kh][4] = (short)f2bf_rne(fmaxf(a1.x * s1.x + h1.x, 0.f));
            bfrag[kh][5] = (short)f2bf_rne(fmaxf(a1.y * s1.y + h1.y, 0.f));
            bfrag[kh][6] = (short)f2bf_rne(fmaxf(a1.z * s1.z + h1.z, 0.f));
            bfrag[kh][7] = (short)f2bf_rne(fmaxf(a1.w * s1.w + h1.w, 0.f));
        }
        float* orow = out + (size_t)row * DIM_OUT;
#pragma unroll
        for (int t = 0; t < 4; ++t) {
            floatx4 acc = {0.f, 0.f, 0.f, 0.f};
            acc = __builtin_amdgcn_mfma_f32_16x16x32_bf16(afrag[t][0], bfrag[0], acc, 0, 0, 0);
            acc = __builtin_amdgcn_mfma_f32_16x16x32_bf16(afrag[t][1], bfrag[1], acc, 0, 0, 0);
            int cc = c0 + t * 16 + quad * 4;
            if (cc < DIM_OUT) {
                float4 o = make_float4(acc[0] + bias[t].x, acc[1] + bias[t].y,
                                       acc[2] + bias[t].z, acc[3] + bias[t].w);
                *reinterpret_cast<float4*>(orow + cc) = o;
            }
        }
    }
}

// ---------------- launch ----------------
extern "C" void kernel_launch(void* const* d_in, const int* in_sizes, int n_in,
                              void* d_out, int out_size, void* d_ws, size_t ws_size,
                              hipStream_t stream) {
    const float* x    = (const float*)d_in[0];
    const int*   ei   = (const int*)  d_in[1];
    const float* W1   = (const float*)d_in[2];
    const float* g1   = (const float*)d_in[4];
    const float* be1  = (const float*)d_in[5];
    const float* W2   = (const float*)d_in[6];
    const float* g2   = (const float*)d_in[8];
    const float* be2  = (const float*)d_in[9];
    const float* att  = (const float*)d_in[10];
    const float* W3   = (const float*)d_in[11];
    const float* g3   = (const float*)d_in[13];
    const float* be3  = (const float*)d_in[14];
    const float* Wout = (const float*)d_in[15];
    const float* bout = (const float*)d_in[16];
    float* out = (float*)d_out;

    char* base = (char*)d_ws;
    size_t off = 0;
    auto alloc = [&](size_t bytes) -> void* {
        void* r = base + off;
        off += (bytes + 255) & ~(size_t)255;
        return r;
    };
    const size_t SSTRIDE = (size_t)N_NODES * DIM_P;   // elements per hop state
    float*  f0      = (float*) alloc((size_t)N_NODES * DIM_H * 4); // z1
    float*  f1      = (float*) alloc((size_t)N_NODES * DIM_H * 4); // z2
    unsigned short* hs = (unsigned short*)alloc((size_t)(KHOPS + 1) * SSTRIDE * 2);
    float*  oa      = (float*) alloc(SSTRIDE * 4);    // fp32 weighted acc
    double* st      = (double*)alloc(640 * 8);
    float*  wts     = (float*) alloc(16 * 4);
    int*    row_ptr = (int*)   alloc((size_t)(N_NODES + 1) * 4);
    int*    deg     = (int*)   alloc((size_t)N_NODES * 4);   // degree -> cursor
    int*    col     = (int*)   alloc((size_t)N_EDGES * 4);
    int*    bsums   = (int*)   alloc(64 * 4);
    unsigned short* WT   = (unsigned short*)alloc((size_t)OUT_PAD * DIM_P * 2);
    unsigned short* WT1h = (unsigned short*)alloc((size_t)DIM_H * DIM_H * 2);
    unsigned short* WT1l = (unsigned short*)alloc((size_t)DIM_H * DIM_H * 2);
    unsigned short* WT2h = (unsigned short*)alloc((size_t)DIM_H * DIM_H * 2);
    unsigned short* WT2l = (unsigned short*)alloc((size_t)DIM_H * DIM_H * 2);
    unsigned short* WT3h = (unsigned short*)alloc((size_t)DIM_P * DIM_H * 2);
    unsigned short* WT3l = (unsigned short*)alloc((size_t)DIM_P * DIM_H * 2);

    const int* src = ei;
    const int* dst = ei + N_EDGES;
    double* st1 = st;   double* st2 = st + 256; double* st3 = st + 512;

    // 1 dispatch: softmax + weight preps (hi/lo splits) + zero stats/deg
    init_all<<<256, 256, 0, stream>>>(att, wts, Wout, WT,
                                      W1, WT1h, WT1l, W2, WT2h, WT2l,
                                      W3, WT3h, WT3l, st, deg);

    // CSR by destination
    count_deg<<<ceil_div(N_EDGES, 256), 256, 0, stream>>>(dst, deg, N_EDGES);
    const int NB = ceil_div(N_NODES, 1024);
    scan_local<<<NB, 1024, 0, stream>>>(deg, row_ptr, bsums, N_NODES);
    scan_finish<<<ceil_div(N_NODES, 256), 256, 0, stream>>>(row_ptr, deg, bsums,
                                                            N_NODES, NB);
    fill_csr<<<ceil_div(N_EDGES, 256), 256, 0, stream>>>(src, dst, deg, col, N_EDGES);

    const int RB = ceil_div(N_NODES, 64);

    // layer 1: z1 = x@W1 via split-bf16 MFMA (fp32-accurate; b1 cancels in BN)
    gemm_mfma_split<128, false, false><<<dim3(RB), 256, 0, stream>>>(
        x, nullptr, nullptr, nullptr,
        nullptr, nullptr, nullptr, nullptr,
        WT1h, WT1l, f0, N_NODES);
    colstats<128><<<256, 256, 0, stream>>>(f0, st1, N_NODES);

    // layer 2: z2 = relu(bn1(z1))@W2 (bn1 finalized in-kernel)
    gemm_mfma_split<128, false, false><<<dim3(RB), 256, 0, stream>>>(
        f0, st1, g1, be1,
        nullptr, nullptr, nullptr, nullptr,
        WT2h, WT2l, f1, N_NODES);
    colstats<128><<<256, 256, 0, stream>>>(f1, st2, N_NODES);

    // layer 3: h2 = relu(bn2(z2)) + relu(bn1(z1)); y = h2@W3 -> hs[0] bf16
    gemm_mfma_split<64, true, true><<<dim3(RB), 256, 0, stream>>>(
        f1, st2, g2, be2,
        f0, st1, g1, be1,
        WT3h, WT3l, (float*)hs, N_NODES);

    // 10 hops over the bf16 state chain hs[i-1] -> hs[i]
    for (int hop = 1; hop <= KHOPS; ++hop) {
        propagate<<<ceil_div(N_NODES, 4), 256, 0, stream>>>(
            hs + (size_t)(hop - 1) * SSTRIDE, hs + (size_t)hop * SSTRIDE,
            row_ptr, col, N_NODES);
    }

    // oa = sum_i w[i]*hs[i] fused with bn3 stats
    wsum_stats<<<256, 256, 0, stream>>>(hs, wts, oa, st3, N_NODES);

    // output: out = relu(bn3(oa)) @ Wout + bout (bn3 fused into the MFMA GEMM)
    out_gemm_mfma<<<dim3(512, 4), 256, 0, stream>>>(oa, st3, g3, be3, WT, bout, out);
}